// Round 4
// baseline (270.788 us; speedup 1.0000x reference)
//
#include <hip/hip_runtime.h>
#include <hip/hip_bf16.h>
#include <math.h>

#define B_    8
#define C_    256
#define N_    16384
#define H_    4
#define D_    32
#define HID_  128
#define ROWS_ 384
#define SCALE 0.17677669529663687f   // 32^-0.5

typedef __attribute__((ext_vector_type(8))) short bf16x8;
typedef __attribute__((ext_vector_type(16))) float f32x16;

__device__ __forceinline__ short f2bf(float f) {
    union { __hip_bfloat16 h; short s; } u;
    u.h = __float2bfloat16(f);
    return u.s;
}

// ------------------------------------------------------------------
// Kernel 0: convert w_qkv [384*256] and w_out [256*128] fp32 -> bf16
// ------------------------------------------------------------------
__global__ void k_conv(const float* __restrict__ wqkv, const float* __restrict__ wout,
                       short* __restrict__ wb)
{
    int i = (blockIdx.x * 256 + threadIdx.x) * 4;
    const float* src = (i < ROWS_ * C_) ? (wqkv + i) : (wout + (i - ROWS_ * C_));
    float4 f = *reinterpret_cast<const float4*>(src);
    short4 s;
    s.x = f2bf(f.x); s.y = f2bf(f.y); s.z = f2bf(f.z); s.w = f2bf(f.w);
    *reinterpret_cast<short4*>(wb + i) = s;
}

// ------------------------------------------------------------------
// Kernel 1: qkv GEMM (MFMA) + q-softmax (-> bf16 q~ [b][n][hid]) +
//           ctx partials via MFMA, accumulated in regs over 4 subtiles,
//           written as per-block partials (NO atomics).
// Grid: 512 blocks = b(8) x q(64); block covers n = q*256 .. +256
// in 4 subtiles of 64 cols. 4 waves; wave wv = head wv.
// ------------------------------------------------------------------
__global__ __launch_bounds__(256, 2) void k_qkv(
    const float* __restrict__ x, const short* __restrict__ wbf,
    short* __restrict__ qtb, float* __restrict__ part)
{
    __shared__ __align__(16) char smA[2][32768];  // double-buffered x tile;
                                                  // cur^1 half also hosts smQ;
                                                  // cur half becomes ek/v after MFMA.

    const int blk = blockIdx.x;
    const int b   = blk >> 6;
    const int qb_ = blk & 63;
    const int n00 = qb_ << 8;
    const int t   = threadIdx.x;
    const int l   = t & 63;
    const int wv  = t >> 6;
    const int c31 = l & 31;
    const int hf  = l >> 5;

    const int kg = t >> 4;             // 0..15
    const int n4 = (t & 15) * 4;
    const float* xb = x + (size_t)b * C_ * N_ + n00 + n4;

    float4 st[16];

#define STAGE_LOAD(NOFF) \
    _Pragma("unroll") \
    for (int it = 0; it < 4; it++) { \
        const float* xp = xb + (size_t)(it * 64 + kg * 4) * N_ + (NOFF); \
        st[it*4+0] = *(const float4*)(xp); \
        st[it*4+1] = *(const float4*)(xp + N_); \
        st[it*4+2] = *(const float4*)(xp + 2*(size_t)N_); \
        st[it*4+3] = *(const float4*)(xp + 3*(size_t)N_); \
    }

#define WRT(DST, K, J, FLD) { short4 sv; \
    sv.x = f2bf(st[0+(K)][FLD]); sv.y = f2bf(st[4+(K)][FLD]); \
    sv.z = f2bf(st[8+(K)][FLD]); sv.w = f2bf(st[12+(K)][FLD]); \
    int n_ = n4 + (J); int kk_ = 0; }
    // (macro above unused; explicit writer below)

#define STAGE_WRITE(DST) \
    _Pragma("unroll") \
    for (int it = 0; it < 4; it++) { \
        const int k_ = it * 64 + kg * 4; \
        float4 r0 = st[it*4+0], r1 = st[it*4+1], r2 = st[it*4+2], r3 = st[it*4+3]; \
        { short4 sv; sv.x=f2bf(r0.x); sv.y=f2bf(r1.x); sv.z=f2bf(r2.x); sv.w=f2bf(r3.x); \
          int n_=n4+0; *(short4*)((DST) + n_*512 + ((2*k_) ^ ((n_&31)<<4))) = sv; } \
        { short4 sv; sv.x=f2bf(r0.y); sv.y=f2bf(r1.y); sv.z=f2bf(r2.y); sv.w=f2bf(r3.y); \
          int n_=n4+1; *(short4*)((DST) + n_*512 + ((2*k_) ^ ((n_&31)<<4))) = sv; } \
        { short4 sv; sv.x=f2bf(r0.z); sv.y=f2bf(r1.z); sv.z=f2bf(r2.z); sv.w=f2bf(r3.z); \
          int n_=n4+2; *(short4*)((DST) + n_*512 + ((2*k_) ^ ((n_&31)<<4))) = sv; } \
        { short4 sv; sv.x=f2bf(r0.w); sv.y=f2bf(r1.w); sv.z=f2bf(r2.w); sv.w=f2bf(r3.w); \
          int n_=n4+3; *(short4*)((DST) + n_*512 + ((2*k_) ^ ((n_&31)<<4))) = sv; } \
    }

    // ---- prologue: stage subtile 0 into buffer 0 ----
    STAGE_LOAD(0)
    STAGE_WRITE(smA[0])
    __syncthreads();

    // ctx accumulators (registers, across all 4 subtiles)
    f32x16 cD, dD;
#pragma unroll
    for (int r = 0; r < 16; r++) { cD[r] = 0.f; dD[r] = 0.f; }
    bf16x8 ones;
#pragma unroll
    for (int i = 0; i < 8; i++) ones[i] = (short)0x3F80;   // bf16 1.0

    int cur = 0;

    for (int sub = 0; sub < 4; sub++) {
        const int n0 = n00 + sub * 64;
        // T14: issue next subtile's loads now; LDS-write them much later
        if (sub < 3) { STAGE_LOAD((sub + 1) * 64) }

        // ---- MFMA K-loop over smA[cur] ----
        f32x16 acc[3][2];
#pragma unroll
        for (int ti = 0; ti < 3; ti++)
#pragma unroll
            for (int ct = 0; ct < 2; ct++)
#pragma unroll
                for (int r = 0; r < 16; r++) acc[ti][ct][r] = 0.f;

        const char* smC = smA[cur];
#pragma unroll
        for (int ks = 0; ks < 16; ks++) {
            const int k0   = ks * 16 + hf * 8;
            const int slot = 2 * ks + hf;
            bf16x8 bfr0 = *(const bf16x8*)(smC + (c31)      * 512 + 16 * (slot ^ c31));
            bf16x8 bfr1 = *(const bf16x8*)(smC + (c31 + 32) * 512 + 16 * (slot ^ c31));
#pragma unroll
            for (int ti = 0; ti < 3; ti++) {
                const int row = (wv + ti * 4) * 32 + c31;
                bf16x8 af = *(const bf16x8*)(wbf + row * C_ + k0);
                acc[ti][0] = __builtin_amdgcn_mfma_f32_32x32x16_bf16(af, bfr0, acc[ti][0], 0, 0, 0);
                acc[ti][1] = __builtin_amdgcn_mfma_f32_32x32x16_bf16(af, bfr1, acc[ti][1], 0, 0, 0);
            }
        }

        // C layout: col = lane&31, row = (r&3)+8*(r>>2)+4*hf

        // ---- q softmax -> smQ (lives in the idle buffer half) ----
        char* smQ = smA[cur ^ 1];
#pragma unroll
        for (int ct = 0; ct < 2; ct++) {
            float mx = -1e30f;
#pragma unroll
            for (int r = 0; r < 16; r++) mx = fmaxf(mx, acc[0][ct][r]);
            mx = fmaxf(mx, __shfl_xor(mx, 32));
            float e[16]; float s = 0.f;
#pragma unroll
            for (int r = 0; r < 16; r++) { e[r] = __expf(acc[0][ct][r] - mx); s += e[r]; }
            s += __shfl_xor(s, 32);
            float inv = SCALE / s;
            const int n = ct * 32 + c31;
#pragma unroll
            for (int r = 0; r < 16; r++) {
                int rm = (r & 3) + 8 * (r >> 2) + 4 * hf;
                int gq = (wv * 32 + rm) >> 2;
                int ad = n * 256 + 8 * (gq ^ (n & 31)) + ((2 * rm) & 7);
                *(short*)(smQ + ad) = f2bf(e[r] * inv);
            }
        }
        __syncthreads();   // MFMA reads of smA[cur] done; smQ visible

        // ---- coalesced q~ store: qtb[b][n0+n][128] ----
        {
            char* qdst = (char*)(qtb + ((size_t)b * N_ + n0) * HID_);
            const int nn  = t >> 4;
            const int c16 = t & 15;
#pragma unroll
            for (int p = 0; p < 4; p++) {
                int n  = p * 16 + nn;
                int g0 = c16 * 2;
                uint2 a0 = *(uint2*)(smQ + n * 256 + 8 * ((g0)     ^ (n & 31)));
                uint2 a1 = *(uint2*)(smQ + n * 256 + 8 * ((g0 + 1) ^ (n & 31)));
                uint4 val; val.x = a0.x; val.y = a0.y; val.z = a1.x; val.w = a1.y;
                *(uint4*)(qdst + n * 256 + c16 * 16) = val;
            }
        }

        // ---- ek/v -> swizzled bf16 tiles (reuse smA[cur]) ----
        char* ekb = smA[cur] + wv * 8192;
        char* vvb = ekb + 4096;
#pragma unroll
        for (int ct = 0; ct < 2; ct++)
#pragma unroll
            for (int r = 0; r < 16; r++) {
                int rm = (r & 3) + 8 * (r >> 2) + 4 * hf;
                int n  = ct * 32 + c31;
                int ad = rm * 128 + ((2 * n) ^ ((rm & 7) << 4));
                *(short*)(ekb + ad) = f2bf(__expf(acc[1][ct][r]));
                *(short*)(vvb + ad) = f2bf(acc[2][ct][r]);
            }
        __syncthreads();   // ek/v visible; smQ reads done

        // ---- ctx MFMA accumulate + write staged regs -> smA[cur^1] ----
#pragma unroll
        for (int ks = 0; ks < 4; ks++) {
            int slot = 2 * ks + hf;
            bf16x8 ea = *(const bf16x8*)(ekb + c31 * 128 + 16 * (slot ^ (c31 & 7)));
            bf16x8 vb = *(const bf16x8*)(vvb + c31 * 128 + 16 * (slot ^ (c31 & 7)));
            cD = __builtin_amdgcn_mfma_f32_32x32x16_bf16(ea, vb,   cD, 0, 0, 0);
            dD = __builtin_amdgcn_mfma_f32_32x32x16_bf16(ea, ones, dD, 0, 0, 0);
        }
        if (sub < 3) { STAGE_WRITE(smA[cur ^ 1]) }
        __syncthreads();   // staged tile visible; ekv reads done
        cur ^= 1;
    }

    // ---- store per-block ctx partials (coalesced, no atomics) ----
    float* pb = part + (size_t)(b * 64 + qb_) * 4224 + wv * 1056;
#pragma unroll
    for (int r = 0; r < 16; r++) {
        int rm = (r & 3) + 8 * (r >> 2) + 4 * hf;
        pb[rm * 33 + c31] = cD[r];
    }
    if (c31 == 0) {
#pragma unroll
        for (int r = 0; r < 16; r++) {
            int rm = (r & 3) + 8 * (r >> 2) + 4 * hf;
            pb[rm * 33 + 32] = dD[r];
        }
    }
#undef STAGE_LOAD
#undef STAGE_WRITE
#undef WRT
}

// ------------------------------------------------------------------
// Kernel 1.5: reduce 64 partials per (b,h), divide by denom,
//             emit bf16 ctx^T [b][h][e][d]
// ------------------------------------------------------------------
__global__ __launch_bounds__(256) void k_red(
    const float* __restrict__ part, short* __restrict__ ctxbf)
{
    __shared__ float buf[1056];
    const int bh = blockIdx.x;            // 32 = b*4 + h
    const int b  = bh >> 2, h = bh & 3;
    const float* p0 = part + (size_t)b * 64 * 4224 + h * 1056;

    for (int i4 = threadIdx.x; i4 < 264; i4 += 256) {
        float4 s = make_float4(0.f, 0.f, 0.f, 0.f);
        const float* pp = p0 + i4 * 4;
#pragma unroll 8
        for (int q = 0; q < 64; q++) {
            float4 v = *(const float4*)(pp + (size_t)q * 4224);
            s.x += v.x; s.y += v.y; s.z += v.z; s.w += v.w;
        }
        *(float4*)(buf + i4 * 4) = s;
    }
    __syncthreads();

    for (int idx = threadIdx.x; idx < 1024; idx += 256) {
        int d = idx >> 5, e = idx & 31;
        float den = buf[d * 33 + 32];
        ctxbf[((size_t)bh * 32 + e) * 32 + d] = f2bf(buf[d * 33 + e] / den);
    }
}

// ------------------------------------------------------------------
// Kernel 2: hidden = ctx^T @ q~ (MFMA, ctx from global bf16),
//           y = w_out @ hidden (MFMA) + bias, RMSNorm over c, store.
// ------------------------------------------------------------------
__global__ __launch_bounds__(256, 3) void k_out(
    const short* __restrict__ qtb, const short* __restrict__ ctxbf,
    const short* __restrict__ woutb, const float* __restrict__ bout,
    const float* __restrict__ g, float* __restrict__ out)
{
    __shared__ __align__(16) char  hidS[16384];        // [n][128] bf16 swz16B
    __shared__ float gl[C_], bl[C_];
    __shared__ float red[4][64];
    __shared__ float nrm[64];

    const int blk = blockIdx.x;
    const int b   = blk >> 8;
    const int n0  = (blk & 255) << 6;
    const int t   = threadIdx.x;
    const int l   = t & 63;
    const int wv  = t >> 6;
    const int c31 = l & 31;
    const int hf  = l >> 5;

    gl[t] = g[t];
    bl[t] = bout[t];
    __syncthreads();

    // ---- hidden MFMA: wave wv -> head wv; hid[e][n] = sum_d ctxT[e][d] q~[d][n]
    f32x16 hD[2];
#pragma unroll
    for (int ct = 0; ct < 2; ct++)
#pragma unroll
        for (int r = 0; r < 16; r++) hD[ct][r] = 0.f;
    const short* qb = qtb + ((size_t)b * N_ + n0) * HID_;
    const short* cb = ctxbf + ((size_t)(b * H_ + wv) * 32 + c31) * 32;
#pragma unroll
    for (int ks = 0; ks < 2; ks++) {
        int k0 = ks * 16 + hf * 8;
        bf16x8 af = *(const bf16x8*)(cb + k0);
#pragma unroll
        for (int ct = 0; ct < 2; ct++) {
            bf16x8 bq = *(const bf16x8*)(qb + (size_t)(ct * 32 + c31) * HID_ + wv * 32 + k0);
            hD[ct] = __builtin_amdgcn_mfma_f32_32x32x16_bf16(af, bq, hD[ct], 0, 0, 0);
        }
    }
    // write hidden -> swizzled LDS [n][hfull]
#pragma unroll
    for (int ct = 0; ct < 2; ct++)
#pragma unroll
        for (int r = 0; r < 16; r++) {
            int rm = (r & 3) + 8 * (r >> 2) + 4 * hf;
            int hfull = wv * 32 + rm;
            int n = ct * 32 + c31;
            int ad = n * 256 + ((2 * hfull) ^ ((n & 15) << 4));
            *(short*)(hidS + ad) = f2bf(hD[ct][r]);
        }
    __syncthreads();

    // ---- w_out GEMM: wave wv -> c rows wv*64..+64 ----
    f32x16 yacc[2][2];
#pragma unroll
    for (int rt = 0; rt < 2; rt++)
#pragma unroll
        for (int ct = 0; ct < 2; ct++)
#pragma unroll
            for (int r = 0; r < 16; r++) yacc[rt][ct][r] = 0.f;

#pragma unroll
    for (int ks = 0; ks < 8; ks++) {
        int k0 = ks * 16 + hf * 8;
        int sx = 2 * ks + hf;
        bf16x8 bq0 = *(const bf16x8*)(hidS + (c31)      * 256 + 16 * (sx ^ (c31 & 15)));
        bf16x8 bq1 = *(const bf16x8*)(hidS + (c31 + 32) * 256 + 16 * (sx ^ (c31 & 15)));
#pragma unroll
        for (int rt = 0; rt < 2; rt++) {
            bf16x8 af = *(const bf16x8*)(woutb + (wv * 64 + rt * 32 + c31) * HID_ + k0);
            yacc[rt][0] = __builtin_amdgcn_mfma_f32_32x32x16_bf16(af, bq0, yacc[rt][0], 0, 0, 0);
            yacc[rt][1] = __builtin_amdgcn_mfma_f32_32x32x16_bf16(af, bq1, yacc[rt][1], 0, 0, 0);
        }
    }

    // ---- bias + RMS over c ----
#pragma unroll
    for (int rt = 0; rt < 2; rt++)
#pragma unroll
        for (int r = 0; r < 16; r++) {
            int rm = (r & 3) + 8 * (r >> 2) + 4 * hf;
            float bo = bl[wv * 64 + rt * 32 + rm];
            yacc[rt][0][r] += bo;
            yacc[rt][1][r] += bo;
        }
#pragma unroll
    for (int ct = 0; ct < 2; ct++) {
        float s = 0.f;
#pragma unroll
        for (int rt = 0; rt < 2; rt++)
#pragma unroll
            for (int r = 0; r < 16; r++) s = fmaf(yacc[rt][ct][r], yacc[rt][ct][r], s);
        s += __shfl_xor(s, 32);
        if (hf == 0) red[wv][ct * 32 + c31] = s;
    }
    __syncthreads();
    if (t < 64) {
        float S = red[0][t] + red[1][t] + red[2][t] + red[3][t];
        nrm[t] = 16.0f / fmaxf(sqrtf(S), 1e-12f);
    }
    __syncthreads();

    float* ob = out + (size_t)b * C_ * N_ + n0;
#pragma unroll
    for (int rt = 0; rt < 2; rt++)
#pragma unroll
        for (int r = 0; r < 16; r++) {
            int rm = (r & 3) + 8 * (r >> 2) + 4 * hf;
            int c  = wv * 64 + rt * 32 + rm;
            float gc = gl[c];
#pragma unroll
            for (int ct = 0; ct < 2; ct++) {
                int n = ct * 32 + c31;
                ob[(size_t)c * N_ + n] = yacc[rt][ct][r] * gc * nrm[n];
            }
        }
}

// ------------------------------------------------------------------
extern "C" void kernel_launch(void* const* d_in, const int* in_sizes, int n_in,
                              void* d_out, int out_size, void* d_ws, size_t ws_size,
                              hipStream_t stream)
{
    const float* x    = (const float*)d_in[0];
    const float* wqkv = (const float*)d_in[1];
    const float* wout = (const float*)d_in[2];
    const float* bout = (const float*)d_in[3];
    const float* g    = (const float*)d_in[4];
    float* out = (float*)d_out;

    // ws: qtb bf16 [B][N][HID] (32 MiB) | part f32 [512][4224] (8.65 MB)
    //   | ctxbf bf16 [B][H][32][32] (64 KB) | w bf16
    short* qtb    = (short*)d_ws;
    float* part   = (float*)((char*)d_ws + (size_t)B_ * N_ * HID_ * 2);
    short* ctxbf  = (short*)((char*)part + (size_t)512 * 4224 * sizeof(float));
    short* wbf    = ctxbf + (size_t)B_ * H_ * 32 * 32;
    short* woutb  = wbf + ROWS_ * C_;

    k_conv<<<(ROWS_ * C_ + C_ * HID_) / 1024, 256, 0, stream>>>(wqkv, wout, wbf);
    k_qkv<<<512, 256, 0, stream>>>(x, wbf, qtb, part);
    k_red<<<B_ * H_, 256, 0, stream>>>(part, ctxbf);
    k_out<<<B_ * (N_ / 64), 256, 0, stream>>>(qtb, ctxbf, woutb, bout, g, out);
}

// Round 5
// 195.942 us; speedup vs baseline: 1.3820x; 1.3820x over previous
//
#include <hip/hip_runtime.h>
#include <hip/hip_bf16.h>
#include <math.h>

#define B_    8
#define C_    256
#define N_    16384
#define H_    4
#define D_    32
#define HID_  128
#define ROWS_ 384
#define SCALE 0.17677669529663687f   // 32^-0.5

typedef __attribute__((ext_vector_type(8))) short bf16x8;
typedef __attribute__((ext_vector_type(16))) float f32x16;

__device__ __forceinline__ short f2bf(float f) {
    union { __hip_bfloat16 h; short s; } u;
    u.h = __float2bfloat16(f);
    return u.s;
}

// ------------------------------------------------------------------
// Kernel 0: convert w_qkv [384*256] and w_out [256*128] fp32 -> bf16
// ------------------------------------------------------------------
__global__ void k_conv(const float* __restrict__ wqkv, const float* __restrict__ wout,
                       short* __restrict__ wb)
{
    int i = (blockIdx.x * 256 + threadIdx.x) * 4;
    const float* src = (i < ROWS_ * C_) ? (wqkv + i) : (wout + (i - ROWS_ * C_));
    float4 f = *reinterpret_cast<const float4*>(src);
    short4 s;
    s.x = f2bf(f.x); s.y = f2bf(f.y); s.z = f2bf(f.z); s.w = f2bf(f.w);
    *reinterpret_cast<short4*>(wb + i) = s;
}

// ------------------------------------------------------------------
// Kernel 1: qkv GEMM (MFMA) + q-softmax (-> bf16 q~ [b][n][hid]) +
//           ctx partials via MFMA accumulated in AGPRs over 4 subtiles,
//           stored coalesced per block (NO atomics, NO held stage regs).
// Grid: 512 = b(8) x q(64); block covers n = q*256..+256 in 4 subtiles.
// 4 waves; wave wv = head wv. LDS 48KB; VGPR target ~70-80 (no spills).
// ------------------------------------------------------------------
__global__ __launch_bounds__(256, 2) void k_qkv(
    const float* __restrict__ x, const short* __restrict__ wbf,
    short* __restrict__ qtb, float* __restrict__ part)
{
    __shared__ __align__(16) char smA[32768];  // x tile [64 n][256 k] bf16 swz16B;
                                               // becomes ek/v tiles after MFMA
    __shared__ __align__(16) char smQ[16384];  // q~ staging [64 n][128 d] bf16 swz8B

    const int blk = blockIdx.x;
    const int b   = blk >> 6;
    const int qb_ = blk & 63;
    const int n00 = qb_ << 8;
    const int t   = threadIdx.x;
    const int l   = t & 63;
    const int wv  = t >> 6;
    const int c31 = l & 31;
    const int hf  = l >> 5;

    const int kg = t >> 4;             // 0..15
    const int n4 = (t & 15) * 4;

    // ctx accumulators (AGPRs, persist across subtiles)
    f32x16 cD, dD;
#pragma unroll
    for (int r = 0; r < 16; r++) { cD[r] = 0.f; dD[r] = 0.f; }
    bf16x8 ones;
#pragma unroll
    for (int i = 0; i < 8; i++) ones[i] = (short)0x3F80;   // bf16 1.0

    for (int sub = 0; sub < 4; sub++) {
        const int n0 = n00 + sub * 64;

        // ---- stage x subtile [256 k][64 n] -> bf16 transposed swizzled ----
        {
            const float* xb = x + (size_t)b * C_ * N_ + n0 + n4;
#pragma unroll
            for (int it = 0; it < 4; it++) {
                const int k = it * 64 + kg * 4;
                const float* xp = xb + (size_t)k * N_;
                float4 r0 = *(const float4*)(xp);
                float4 r1 = *(const float4*)(xp + N_);
                float4 r2 = *(const float4*)(xp + 2 * (size_t)N_);
                float4 r3 = *(const float4*)(xp + 3 * (size_t)N_);
#define WRT(J, FLD) { short4 sv; sv.x = f2bf(r0.FLD); sv.y = f2bf(r1.FLD); \
    sv.z = f2bf(r2.FLD); sv.w = f2bf(r3.FLD); \
    int n_ = n4 + J; int ad_ = n_ * 512 + ((2 * k) ^ ((n_ & 31) << 4)); \
    *(short4*)(smA + ad_) = sv; }
                WRT(0, x) WRT(1, y) WRT(2, z) WRT(3, w)
#undef WRT
            }
        }
        __syncthreads();

        // ---- MFMA K-loop: 16 k-steps of 16 ----
        f32x16 acc[3][2];
#pragma unroll
        for (int ti = 0; ti < 3; ti++)
#pragma unroll
            for (int ct = 0; ct < 2; ct++)
#pragma unroll
                for (int r = 0; r < 16; r++) acc[ti][ct][r] = 0.f;

#pragma unroll
        for (int ks = 0; ks < 16; ks++) {
            const int k0   = ks * 16 + hf * 8;
            const int slot = 2 * ks + hf;
            bf16x8 bfr0 = *(const bf16x8*)(smA + (c31)      * 512 + 16 * (slot ^ c31));
            bf16x8 bfr1 = *(const bf16x8*)(smA + (c31 + 32) * 512 + 16 * (slot ^ c31));
#pragma unroll
            for (int ti = 0; ti < 3; ti++) {
                const int row = (wv + ti * 4) * 32 + c31;
                bf16x8 af = *(const bf16x8*)(wbf + row * C_ + k0);
                acc[ti][0] = __builtin_amdgcn_mfma_f32_32x32x16_bf16(af, bfr0, acc[ti][0], 0, 0, 0);
                acc[ti][1] = __builtin_amdgcn_mfma_f32_32x32x16_bf16(af, bfr1, acc[ti][1], 0, 0, 0);
            }
        }

        // C layout: col = lane&31, row = (r&3)+8*(r>>2)+4*hf

        // ---- q softmax -> smQ (transposed, 8B-swizzled) ----
#pragma unroll
        for (int ct = 0; ct < 2; ct++) {
            float mx = -1e30f;
#pragma unroll
            for (int r = 0; r < 16; r++) mx = fmaxf(mx, acc[0][ct][r]);
            mx = fmaxf(mx, __shfl_xor(mx, 32));
            float e[16]; float s = 0.f;
#pragma unroll
            for (int r = 0; r < 16; r++) { e[r] = __expf(acc[0][ct][r] - mx); s += e[r]; }
            s += __shfl_xor(s, 32);
            float inv = SCALE / s;
            const int n = ct * 32 + c31;
#pragma unroll
            for (int r = 0; r < 16; r++) {
                int rm = (r & 3) + 8 * (r >> 2) + 4 * hf;
                int gq = (wv * 32 + rm) >> 2;
                int ad = n * 256 + 8 * (gq ^ (n & 31)) + ((2 * rm) & 7);
                *(short*)(smQ + ad) = f2bf(e[r] * inv);
            }
        }
        __syncthreads();   // smA MFMA reads done; smQ visible

        // ---- coalesced q~ store: qtb[b][n0+n][128] ----
        {
            char* qdst = (char*)(qtb + ((size_t)b * N_ + n0) * HID_);
            const int nn  = t >> 4;
            const int c16 = t & 15;
#pragma unroll
            for (int p = 0; p < 4; p++) {
                int n  = p * 16 + nn;
                int g0 = c16 * 2;
                uint2 a0 = *(uint2*)(smQ + n * 256 + 8 * ((g0)     ^ (n & 31)));
                uint2 a1 = *(uint2*)(smQ + n * 256 + 8 * ((g0 + 1) ^ (n & 31)));
                uint4 val; val.x = a0.x; val.y = a0.y; val.z = a1.x; val.w = a1.y;
                *(uint4*)(qdst + n * 256 + c16 * 16) = val;
            }
        }

        // ---- ek/v -> swizzled bf16 tiles (reuse smA) ----
        char* ekb = smA + wv * 8192;
        char* vvb = ekb + 4096;
#pragma unroll
        for (int ct = 0; ct < 2; ct++)
#pragma unroll
            for (int r = 0; r < 16; r++) {
                int rm = (r & 3) + 8 * (r >> 2) + 4 * hf;
                int n  = ct * 32 + c31;
                int ad = rm * 128 + ((2 * n) ^ ((rm & 7) << 4));
                *(short*)(ekb + ad) = f2bf(__expf(acc[1][ct][r]));
                *(short*)(vvb + ad) = f2bf(acc[2][ct][r]);
            }
        __syncthreads();   // ek/v visible; smQ reads done

        // ---- ctx MFMA accumulate (into persistent AGPRs) ----
#pragma unroll
        for (int ks = 0; ks < 4; ks++) {
            int slot = 2 * ks + hf;
            bf16x8 ea = *(const bf16x8*)(ekb + c31 * 128 + 16 * (slot ^ (c31 & 7)));
            bf16x8 vb = *(const bf16x8*)(vvb + c31 * 128 + 16 * (slot ^ (c31 & 7)));
            cD = __builtin_amdgcn_mfma_f32_32x32x16_bf16(ea, vb,   cD, 0, 0, 0);
            dD = __builtin_amdgcn_mfma_f32_32x32x16_bf16(ea, ones, dD, 0, 0, 0);
        }
        __syncthreads();   // ekv reads done; smA free for next stage
    }

    // ---- store per-block ctx partials (coalesced, no atomics) ----
    float* pb = part + (size_t)blk * 4224 + wv * 1056;
#pragma unroll
    for (int r = 0; r < 16; r++) {
        int rm = (r & 3) + 8 * (r >> 2) + 4 * hf;
        pb[rm * 33 + c31] = cD[r];
    }
    if (c31 == 0) {
#pragma unroll
        for (int r = 0; r < 16; r++) {
            int rm = (r & 3) + 8 * (r >> 2) + 4 * hf;
            pb[rm * 33 + 32] = dD[r];
        }
    }
}

// ------------------------------------------------------------------
// Kernel 1.5: reduce 64 partials per (b,h), divide by denom,
//             emit bf16 ctx^T [b][h][e][d]
// ------------------------------------------------------------------
__global__ __launch_bounds__(256) void k_red(
    const float* __restrict__ part, short* __restrict__ ctxbf)
{
    __shared__ float buf[1056];
    const int bh = blockIdx.x;            // 32 = b*4 + h
    const int b  = bh >> 2, h = bh & 3;
    const float* p0 = part + (size_t)b * 64 * 4224 + h * 1056;

    for (int i4 = threadIdx.x; i4 < 264; i4 += 256) {
        float4 s = make_float4(0.f, 0.f, 0.f, 0.f);
        const float* pp = p0 + i4 * 4;
#pragma unroll 8
        for (int q = 0; q < 64; q++) {
            float4 v = *(const float4*)(pp + (size_t)q * 4224);
            s.x += v.x; s.y += v.y; s.z += v.z; s.w += v.w;
        }
        *(float4*)(buf + i4 * 4) = s;
    }
    __syncthreads();

    for (int idx = threadIdx.x; idx < 1024; idx += 256) {
        int d = idx >> 5, e = idx & 31;
        float den = buf[d * 33 + 32];
        ctxbf[((size_t)bh * 32 + e) * 32 + d] = f2bf(buf[d * 33 + e] / den);
    }
}

// ------------------------------------------------------------------
// Kernel 2: hidden = ctx^T @ q~ (MFMA, ctx from global bf16),
//           y = w_out @ hidden (MFMA) + bias, RMSNorm over c, store.
// ------------------------------------------------------------------
__global__ __launch_bounds__(256, 3) void k_out(
    const short* __restrict__ qtb, const short* __restrict__ ctxbf,
    const short* __restrict__ woutb, const float* __restrict__ bout,
    const float* __restrict__ g, float* __restrict__ out)
{
    __shared__ __align__(16) char  hidS[16384];        // [n][128] bf16 swz16B
    __shared__ float gl[C_], bl[C_];
    __shared__ float red[4][64];
    __shared__ float nrm[64];

    const int blk = blockIdx.x;
    const int b   = blk >> 8;
    const int n0  = (blk & 255) << 6;
    const int t   = threadIdx.x;
    const int l   = t & 63;
    const int wv  = t >> 6;
    const int c31 = l & 31;
    const int hf  = l >> 5;

    gl[t] = g[t];
    bl[t] = bout[t];
    __syncthreads();

    // ---- hidden MFMA: wave wv -> head wv; hid[e][n] = sum_d ctxT[e][d] q~[d][n]
    f32x16 hD[2];
#pragma unroll
    for (int ct = 0; ct < 2; ct++)
#pragma unroll
        for (int r = 0; r < 16; r++) hD[ct][r] = 0.f;
    const short* qb = qtb + ((size_t)b * N_ + n0) * HID_;
    const short* cb = ctxbf + ((size_t)(b * H_ + wv) * 32 + c31) * 32;
#pragma unroll
    for (int ks = 0; ks < 2; ks++) {
        int k0 = ks * 16 + hf * 8;
        bf16x8 af = *(const bf16x8*)(cb + k0);
#pragma unroll
        for (int ct = 0; ct < 2; ct++) {
            bf16x8 bq = *(const bf16x8*)(qb + (size_t)(ct * 32 + c31) * HID_ + wv * 32 + k0);
            hD[ct] = __builtin_amdgcn_mfma_f32_32x32x16_bf16(af, bq, hD[ct], 0, 0, 0);
        }
    }
    // write hidden -> swizzled LDS [n][hfull]
#pragma unroll
    for (int ct = 0; ct < 2; ct++)
#pragma unroll
        for (int r = 0; r < 16; r++) {
            int rm = (r & 3) + 8 * (r >> 2) + 4 * hf;
            int hfull = wv * 32 + rm;
            int n = ct * 32 + c31;
            int ad = n * 256 + ((2 * hfull) ^ ((n & 15) << 4));
            *(short*)(hidS + ad) = f2bf(hD[ct][r]);
        }
    __syncthreads();

    // ---- w_out GEMM: wave wv -> c rows wv*64..+64 ----
    f32x16 yacc[2][2];
#pragma unroll
    for (int rt = 0; rt < 2; rt++)
#pragma unroll
        for (int ct = 0; ct < 2; ct++)
#pragma unroll
            for (int r = 0; r < 16; r++) yacc[rt][ct][r] = 0.f;

#pragma unroll
    for (int ks = 0; ks < 8; ks++) {
        int k0 = ks * 16 + hf * 8;
        int sx = 2 * ks + hf;
        bf16x8 bq0 = *(const bf16x8*)(hidS + (c31)      * 256 + 16 * (sx ^ (c31 & 15)));
        bf16x8 bq1 = *(const bf16x8*)(hidS + (c31 + 32) * 256 + 16 * (sx ^ (c31 & 15)));
#pragma unroll
        for (int rt = 0; rt < 2; rt++) {
            bf16x8 af = *(const bf16x8*)(woutb + (wv * 64 + rt * 32 + c31) * HID_ + k0);
            yacc[rt][0] = __builtin_amdgcn_mfma_f32_32x32x16_bf16(af, bq0, yacc[rt][0], 0, 0, 0);
            yacc[rt][1] = __builtin_amdgcn_mfma_f32_32x32x16_bf16(af, bq1, yacc[rt][1], 0, 0, 0);
        }
    }

    // ---- bias + RMS over c ----
#pragma unroll
    for (int rt = 0; rt < 2; rt++)
#pragma unroll
        for (int r = 0; r < 16; r++) {
            int rm = (r & 3) + 8 * (r >> 2) + 4 * hf;
            float bo = bl[wv * 64 + rt * 32 + rm];
            yacc[rt][0][r] += bo;
            yacc[rt][1][r] += bo;
        }
#pragma unroll
    for (int ct = 0; ct < 2; ct++) {
        float s = 0.f;
#pragma unroll
        for (int rt = 0; rt < 2; rt++)
#pragma unroll
            for (int r = 0; r < 16; r++) s = fmaf(yacc[rt][ct][r], yacc[rt][ct][r], s);
        s += __shfl_xor(s, 32);
        if (hf == 0) red[wv][ct * 32 + c31] = s;
    }
    __syncthreads();
    if (t < 64) {
        float S = red[0][t] + red[1][t] + red[2][t] + red[3][t];
        nrm[t] = 16.0f / fmaxf(sqrtf(S), 1e-12f);
    }
    __syncthreads();

    float* ob = out + (size_t)b * C_ * N_ + n0;
#pragma unroll
    for (int rt = 0; rt < 2; rt++)
#pragma unroll
        for (int r = 0; r < 16; r++) {
            int rm = (r & 3) + 8 * (r >> 2) + 4 * hf;
            int c  = wv * 64 + rt * 32 + rm;
            float gc = gl[c];
#pragma unroll
            for (int ct = 0; ct < 2; ct++) {
                int n = ct * 32 + c31;
                ob[(size_t)c * N_ + n] = yacc[rt][ct][r] * gc * nrm[n];
            }
        }
}

// ------------------------------------------------------------------
extern "C" void kernel_launch(void* const* d_in, const int* in_sizes, int n_in,
                              void* d_out, int out_size, void* d_ws, size_t ws_size,
                              hipStream_t stream)
{
    const float* x    = (const float*)d_in[0];
    const float* wqkv = (const float*)d_in[1];
    const float* wout = (const float*)d_in[2];
    const float* bout = (const float*)d_in[3];
    const float* g    = (const float*)d_in[4];
    float* out = (float*)d_out;

    // ws: qtb bf16 [B][N][HID] (32 MiB) | part f32 [512][4224] (8.65 MB)
    //   | ctxbf bf16 [B][H][32][32] (64 KB) | w bf16
    short* qtb    = (short*)d_ws;
    float* part   = (float*)((char*)d_ws + (size_t)B_ * N_ * HID_ * 2);
    short* ctxbf  = (short*)((char*)part + (size_t)512 * 4224 * sizeof(float));
    short* wbf    = ctxbf + (size_t)B_ * H_ * 32 * 32;
    short* woutb  = wbf + ROWS_ * C_;

    k_conv<<<(ROWS_ * C_ + C_ * HID_) / 1024, 256, 0, stream>>>(wqkv, wout, wbf);
    k_qkv<<<512, 256, 0, stream>>>(x, wbf, qtb, part);
    k_red<<<B_ * H_, 256, 0, stream>>>(part, ctxbf);
    k_out<<<B_ * (N_ / 64), 256, 0, stream>>>(qtb, ctxbf, woutb, bout, g, out);
}

// Round 6
// 155.865 us; speedup vs baseline: 1.7373x; 1.2571x over previous
//
#include <hip/hip_runtime.h>
#include <hip/hip_bf16.h>
#include <math.h>

#define B_    8
#define C_    256
#define N_    16384
#define H_    4
#define D_    32
#define HID_  128
#define ROWS_ 384
#define SCALE 0.17677669529663687f   // 32^-0.5

typedef __attribute__((ext_vector_type(8))) short bf16x8;
typedef __attribute__((ext_vector_type(16))) float f32x16;

__device__ __forceinline__ short f2bf(float f) {
    union { __hip_bfloat16 h; short s; } u;
    u.h = __float2bfloat16(f);
    return u.s;
}
__device__ __forceinline__ float bf2f(short s) {
    union { unsigned u; float f; } x;
    x.u = ((unsigned)(unsigned short)s) << 16;
    return x.f;
}

// ------------------------------------------------------------------
// Kernel 0: convert w_qkv [384*256] and w_out [256*128] fp32 -> bf16
// ------------------------------------------------------------------
__global__ void k_conv(const float* __restrict__ wqkv, const float* __restrict__ wout,
                       short* __restrict__ wb)
{
    int i = (blockIdx.x * 256 + threadIdx.x) * 4;
    const float* src = (i < ROWS_ * C_) ? (wqkv + i) : (wout + (i - ROWS_ * C_));
    float4 f = *reinterpret_cast<const float4*>(src);
    short4 s;
    s.x = f2bf(f.x); s.y = f2bf(f.y); s.z = f2bf(f.z); s.w = f2bf(f.w);
    *reinterpret_cast<short4*>(wb + i) = s;
}

// ------------------------------------------------------------------
// Kernel 1: EXACT round-3 structure (68 VGPR, no spills), single
// 64-col subtile per block, grid 2048. ONLY change: ctx partials are
// stored coalesced per block (bf16 ctx + f32 den) -- NO atomics.
// ------------------------------------------------------------------
__global__ __launch_bounds__(256, 2) void k_qkv(
    const float* __restrict__ x, const short* __restrict__ wbf,
    short* __restrict__ qtb, short* __restrict__ part16,
    float* __restrict__ partden)
{
    __shared__ __align__(16) char smA[32768];  // x tile [64 n][256 k] bf16 swz16B;
                                               // becomes ek/v tiles after MFMA
    __shared__ __align__(16) char smQ[16384];  // q~ staging [64 n][128 d] bf16 swz8B

    const int blk = blockIdx.x;
    const int b   = blk >> 8;              // 256 col-blocks per batch
    const int n0  = (blk & 255) << 6;
    const int t   = threadIdx.x;
    const int l   = t & 63;
    const int wv  = t >> 6;
    const int c31 = l & 31;
    const int hf  = l >> 5;

    // ---- stage x tile [256 k][64 n] -> bf16 transposed swizzled [n][k] ----
    {
        const int kg = t >> 4;             // 0..15
        const int n4 = (t & 15) * 4;
        const float* xb = x + (size_t)b * C_ * N_ + n0 + n4;
#pragma unroll
        for (int it = 0; it < 4; it++) {
            const int k = it * 64 + kg * 4;
            const float* xp = xb + (size_t)k * N_;
            float4 r0 = *(const float4*)(xp);
            float4 r1 = *(const float4*)(xp + N_);
            float4 r2 = *(const float4*)(xp + 2 * (size_t)N_);
            float4 r3 = *(const float4*)(xp + 3 * (size_t)N_);
#define WRT(J, FLD) { short4 sv; sv.x = f2bf(r0.FLD); sv.y = f2bf(r1.FLD); \
    sv.z = f2bf(r2.FLD); sv.w = f2bf(r3.FLD); \
    int n_ = n4 + J; int ad_ = n_ * 512 + ((2 * k) ^ ((n_ & 31) << 4)); \
    *(short4*)(smA + ad_) = sv; }
            WRT(0, x) WRT(1, y) WRT(2, z) WRT(3, w)
#undef WRT
        }
    }
    __syncthreads();

    // ---- MFMA K-loop: 16 k-steps of 16 ----
    f32x16 acc[3][2];
#pragma unroll
    for (int ti = 0; ti < 3; ti++)
#pragma unroll
        for (int ct = 0; ct < 2; ct++)
#pragma unroll
            for (int r = 0; r < 16; r++) acc[ti][ct][r] = 0.f;

#pragma unroll
    for (int ks = 0; ks < 16; ks++) {
        const int k0   = ks * 16 + hf * 8;
        const int slot = 2 * ks + hf;
        bf16x8 bfr0 = *(const bf16x8*)(smA + (c31)      * 512 + 16 * (slot ^ c31));
        bf16x8 bfr1 = *(const bf16x8*)(smA + (c31 + 32) * 512 + 16 * (slot ^ c31));
#pragma unroll
        for (int ti = 0; ti < 3; ti++) {
            const int row = (wv + ti * 4) * 32 + c31;
            bf16x8 af = *(const bf16x8*)(wbf + row * C_ + k0);
            acc[ti][0] = __builtin_amdgcn_mfma_f32_32x32x16_bf16(af, bfr0, acc[ti][0], 0, 0, 0);
            acc[ti][1] = __builtin_amdgcn_mfma_f32_32x32x16_bf16(af, bfr1, acc[ti][1], 0, 0, 0);
        }
    }

    // C layout: col = lane&31, row = (r&3)+8*(r>>2)+4*hf

    // ---- q softmax -> smQ (transposed, 8B-swizzled) ----
#pragma unroll
    for (int ct = 0; ct < 2; ct++) {
        float mx = -1e30f;
#pragma unroll
        for (int r = 0; r < 16; r++) mx = fmaxf(mx, acc[0][ct][r]);
        mx = fmaxf(mx, __shfl_xor(mx, 32));
        float e[16]; float s = 0.f;
#pragma unroll
        for (int r = 0; r < 16; r++) { e[r] = __expf(acc[0][ct][r] - mx); s += e[r]; }
        s += __shfl_xor(s, 32);
        float inv = SCALE / s;
        const int n = ct * 32 + c31;
#pragma unroll
        for (int r = 0; r < 16; r++) {
            int rm = (r & 3) + 8 * (r >> 2) + 4 * hf;
            int gq = (wv * 32 + rm) >> 2;
            int ad = n * 256 + 8 * (gq ^ (n & 31)) + ((2 * rm) & 7);
            *(short*)(smQ + ad) = f2bf(e[r] * inv);
        }
    }
    __syncthreads();   // smA MFMA reads done; smQ visible

    // ---- coalesced q~ store: qtb[b][n0+n][128] ----
    {
        char* qdst = (char*)(qtb + ((size_t)b * N_ + n0) * HID_);
        const int nn  = t >> 4;
        const int c16 = t & 15;
#pragma unroll
        for (int p = 0; p < 4; p++) {
            int n  = p * 16 + nn;
            int g0 = c16 * 2;
            uint2 a0 = *(uint2*)(smQ + n * 256 + 8 * ((g0)     ^ (n & 31)));
            uint2 a1 = *(uint2*)(smQ + n * 256 + 8 * ((g0 + 1) ^ (n & 31)));
            uint4 val; val.x = a0.x; val.y = a0.y; val.z = a1.x; val.w = a1.y;
            *(uint4*)(qdst + n * 256 + c16 * 16) = val;
        }
    }

    // ---- ek/v -> swizzled bf16 tiles (reuse smA) ----
    char* ekb = smA + wv * 8192;
    char* vvb = ekb + 4096;
#pragma unroll
    for (int ct = 0; ct < 2; ct++)
#pragma unroll
        for (int r = 0; r < 16; r++) {
            int rm = (r & 3) + 8 * (r >> 2) + 4 * hf;
            int n  = ct * 32 + c31;
            int ad = rm * 128 + ((2 * n) ^ ((rm & 7) << 4));
            *(short*)(ekb + ad) = f2bf(__expf(acc[1][ct][r]));
            *(short*)(vvb + ad) = f2bf(acc[2][ct][r]);
        }
    __syncthreads();   // ek/v visible; smQ reads done

    // ---- ctx MFMA: ctx[d][e] = sum_n ek[d,n] v[e,n] (this block's 64 n) ----
    f32x16 cD, dD;
#pragma unroll
    for (int r = 0; r < 16; r++) { cD[r] = 0.f; dD[r] = 0.f; }
    bf16x8 ones;
#pragma unroll
    for (int i = 0; i < 8; i++) ones[i] = (short)0x3F80;   // bf16 1.0
#pragma unroll
    for (int ks = 0; ks < 4; ks++) {
        int slot = 2 * ks + hf;
        bf16x8 ea = *(const bf16x8*)(ekb + c31 * 128 + 16 * (slot ^ (c31 & 7)));
        bf16x8 vb = *(const bf16x8*)(vvb + c31 * 128 + 16 * (slot ^ (c31 & 7)));
        cD = __builtin_amdgcn_mfma_f32_32x32x16_bf16(ea, vb,   cD, 0, 0, 0);
        dD = __builtin_amdgcn_mfma_f32_32x32x16_bf16(ea, ones, dD, 0, 0, 0);
    }

    // ---- store per-block ctx partials: bf16 ctx + f32 den (NO atomics) ----
    short* pb = part16 + ((size_t)blk * 4 + wv) * 1024;
#pragma unroll
    for (int r = 0; r < 16; r++) {
        int rm = (r & 3) + 8 * (r >> 2) + 4 * hf;
        pb[rm * 32 + c31] = f2bf(cD[r]);
    }
    if (c31 == 0) {
        float* pd = partden + ((size_t)blk * 4 + wv) * 32;
#pragma unroll
        for (int r = 0; r < 16; r++) {
            int rm = (r & 3) + 8 * (r >> 2) + 4 * hf;
            pd[rm] = dD[r];
        }
    }
}

// ------------------------------------------------------------------
// Kernel 1.5: reduce 256 partials per (b,h), divide by denom,
//             emit bf16 ctx^T [b][h][e][d]
// ------------------------------------------------------------------
__global__ __launch_bounds__(256) void k_red(
    const short* __restrict__ part16, const float* __restrict__ partden,
    short* __restrict__ ctxbf)
{
    __shared__ float den_s[32];
    const int bh = blockIdx.x;            // 32 = b*4 + h
    const int b  = bh >> 2, h = bh & 3;
    const int t  = threadIdx.x;
    const int d  = t >> 3;
    const int e4 = (t & 7) * 4;

    const short* p0 = part16 + ((size_t)(b * 256) * 4 + h) * 1024 + d * 32 + e4;
    float s0 = 0.f, s1 = 0.f, s2 = 0.f, s3 = 0.f;
    for (int q = 0; q < 256; q++) {
        short4 v = *(const short4*)(p0 + (size_t)q * 4096);
        s0 += bf2f(v.x); s1 += bf2f(v.y); s2 += bf2f(v.z); s3 += bf2f(v.w);
    }
    if ((t & 7) == 0) {
        const float* pd = partden + ((size_t)(b * 256) * 4 + h) * 32 + d;
        float ds = 0.f;
        for (int q = 0; q < 256; q++) ds += pd[(size_t)q * 128];
        den_s[d] = ds;
    }
    __syncthreads();
    float inv = 1.0f / den_s[d];
    short* cb = ctxbf + (size_t)bh * 1024 + d;     // [e][d] layout
    cb[(e4 + 0) * 32] = f2bf(s0 * inv);
    cb[(e4 + 1) * 32] = f2bf(s1 * inv);
    cb[(e4 + 2) * 32] = f2bf(s2 * inv);
    cb[(e4 + 3) * 32] = f2bf(s3 * inv);
}

// ------------------------------------------------------------------
// Kernel 2: hidden = ctx^T @ q~ (MFMA, ctx from global bf16),
//           y = w_out @ hidden (MFMA) + bias, RMSNorm over c, store.
// ------------------------------------------------------------------
__global__ __launch_bounds__(256, 3) void k_out(
    const short* __restrict__ qtb, const short* __restrict__ ctxbf,
    const short* __restrict__ woutb, const float* __restrict__ bout,
    const float* __restrict__ g, float* __restrict__ out)
{
    __shared__ __align__(16) char  hidS[16384];        // [n][128] bf16 swz16B
    __shared__ float gl[C_], bl[C_];
    __shared__ float red[4][64];
    __shared__ float nrm[64];

    const int blk = blockIdx.x;
    const int b   = blk >> 8;
    const int n0  = (blk & 255) << 6;
    const int t   = threadIdx.x;
    const int l   = t & 63;
    const int wv  = t >> 6;
    const int c31 = l & 31;
    const int hf  = l >> 5;

    gl[t] = g[t];
    bl[t] = bout[t];
    __syncthreads();

    // ---- hidden MFMA: wave wv -> head wv; hid[e][n] = sum_d ctxT[e][d] q~[d][n]
    f32x16 hD[2];
#pragma unroll
    for (int ct = 0; ct < 2; ct++)
#pragma unroll
        for (int r = 0; r < 16; r++) hD[ct][r] = 0.f;
    const short* qb = qtb + ((size_t)b * N_ + n0) * HID_;
    const short* cb = ctxbf + ((size_t)(b * H_ + wv) * 32 + c31) * 32;
#pragma unroll
    for (int ks = 0; ks < 2; ks++) {
        int k0 = ks * 16 + hf * 8;
        bf16x8 af = *(const bf16x8*)(cb + k0);
#pragma unroll
        for (int ct = 0; ct < 2; ct++) {
            bf16x8 bq = *(const bf16x8*)(qb + (size_t)(ct * 32 + c31) * HID_ + wv * 32 + k0);
            hD[ct] = __builtin_amdgcn_mfma_f32_32x32x16_bf16(af, bq, hD[ct], 0, 0, 0);
        }
    }
    // write hidden -> swizzled LDS [n][hfull]
#pragma unroll
    for (int ct = 0; ct < 2; ct++)
#pragma unroll
        for (int r = 0; r < 16; r++) {
            int rm = (r & 3) + 8 * (r >> 2) + 4 * hf;
            int hfull = wv * 32 + rm;
            int n = ct * 32 + c31;
            int ad = n * 256 + ((2 * hfull) ^ ((n & 15) << 4));
            *(short*)(hidS + ad) = f2bf(hD[ct][r]);
        }
    __syncthreads();

    // ---- w_out GEMM: wave wv -> c rows wv*64..+64 ----
    f32x16 yacc[2][2];
#pragma unroll
    for (int rt = 0; rt < 2; rt++)
#pragma unroll
        for (int ct = 0; ct < 2; ct++)
#pragma unroll
            for (int r = 0; r < 16; r++) yacc[rt][ct][r] = 0.f;

#pragma unroll
    for (int ks = 0; ks < 8; ks++) {
        int k0 = ks * 16 + hf * 8;
        int sx = 2 * ks + hf;
        bf16x8 bq0 = *(const bf16x8*)(hidS + (c31)      * 256 + 16 * (sx ^ (c31 & 15)));
        bf16x8 bq1 = *(const bf16x8*)(hidS + (c31 + 32) * 256 + 16 * (sx ^ (c31 & 15)));
#pragma unroll
        for (int rt = 0; rt < 2; rt++) {
            bf16x8 af = *(const bf16x8*)(woutb + (wv * 64 + rt * 32 + c31) * HID_ + k0);
            yacc[rt][0] = __builtin_amdgcn_mfma_f32_32x32x16_bf16(af, bq0, yacc[rt][0], 0, 0, 0);
            yacc[rt][1] = __builtin_amdgcn_mfma_f32_32x32x16_bf16(af, bq1, yacc[rt][1], 0, 0, 0);
        }
    }

    // ---- bias + RMS over c ----
#pragma unroll
    for (int rt = 0; rt < 2; rt++)
#pragma unroll
        for (int r = 0; r < 16; r++) {
            int rm = (r & 3) + 8 * (r >> 2) + 4 * hf;
            float bo = bl[wv * 64 + rt * 32 + rm];
            yacc[rt][0][r] += bo;
            yacc[rt][1][r] += bo;
        }
#pragma unroll
    for (int ct = 0; ct < 2; ct++) {
        float s = 0.f;
#pragma unroll
        for (int rt = 0; rt < 2; rt++)
#pragma unroll
            for (int r = 0; r < 16; r++) s = fmaf(yacc[rt][ct][r], yacc[rt][ct][r], s);
        s += __shfl_xor(s, 32);
        if (hf == 0) red[wv][ct * 32 + c31] = s;
    }
    __syncthreads();
    if (t < 64) {
        float S = red[0][t] + red[1][t] + red[2][t] + red[3][t];
        nrm[t] = 16.0f / fmaxf(sqrtf(S), 1e-12f);
    }
    __syncthreads();

    float* ob = out + (size_t)b * C_ * N_ + n0;
#pragma unroll
    for (int rt = 0; rt < 2; rt++)
#pragma unroll
        for (int r = 0; r < 16; r++) {
            int rm = (r & 3) + 8 * (r >> 2) + 4 * hf;
            int c  = wv * 64 + rt * 32 + rm;
            float gc = gl[c];
#pragma unroll
            for (int ct = 0; ct < 2; ct++) {
                int n = ct * 32 + c31;
                ob[(size_t)c * N_ + n] = yacc[rt][ct][r] * gc * nrm[n];
            }
        }
}

// ------------------------------------------------------------------
extern "C" void kernel_launch(void* const* d_in, const int* in_sizes, int n_in,
                              void* d_out, int out_size, void* d_ws, size_t ws_size,
                              hipStream_t stream)
{
    const float* x    = (const float*)d_in[0];
    const float* wqkv = (const float*)d_in[1];
    const float* wout = (const float*)d_in[2];
    const float* bout = (const float*)d_in[3];
    const float* g    = (const float*)d_in[4];
    float* out = (float*)d_out;

    // ws: qtb bf16 [B][N][HID] (33.6 MB) | part16 bf16 [2048][4][1024] (16.8 MB)
    //   | partden f32 [2048][4][32] (1.05 MB) | ctxbf bf16 [B][H][32][32] (64 KB)
    //   | w bf16 (~0.26 MB)   => ~51.8 MB total
    short* qtb     = (short*)d_ws;
    short* part16  = qtb + (size_t)B_ * N_ * HID_;
    float* partden = (float*)(part16 + (size_t)2048 * 4 * 1024);
    short* ctxbf   = (short*)(partden + (size_t)2048 * 4 * 32);
    short* wbf     = ctxbf + (size_t)B_ * H_ * 32 * 32;
    short* woutb   = wbf + ROWS_ * C_;

    k_conv<<<(ROWS_ * C_ + C_ * HID_) / 1024, 256, 0, stream>>>(wqkv, wout, wbf);
    k_qkv<<<B_ * (N_ / 64), 256, 0, stream>>>(x, wbf, qtb, part16, partden);
    k_red<<<B_ * H_, 256, 0, stream>>>(part16, partden, ctxbf);
    k_out<<<B_ * (N_ / 64), 256, 0, stream>>>(qtb, ctxbf, woutb, bout, g, out);
}

// Round 7
// 151.920 us; speedup vs baseline: 1.7824x; 1.0260x over previous
//
#include <hip/hip_runtime.h>
#include <hip/hip_bf16.h>
#include <math.h>

#define B_    8
#define C_    256
#define N_    16384
#define H_    4
#define D_    32
#define HID_  128
#define ROWS_ 384
#define SCALE 0.17677669529663687f   // 32^-0.5

typedef __attribute__((ext_vector_type(8))) short bf16x8;
typedef __attribute__((ext_vector_type(16))) float f32x16;

__device__ __forceinline__ short f2bf(float f) {
    union { __hip_bfloat16 h; short s; } u;
    u.h = __float2bfloat16(f);
    return u.s;
}
__device__ __forceinline__ float bf2f(short s) {
    union { unsigned u; float f; } x;
    x.u = ((unsigned)(unsigned short)s) << 16;
    return x.f;
}

// ------------------------------------------------------------------
// Kernel 0: convert w_qkv [384*256] and w_out [256*128] fp32 -> bf16
// ------------------------------------------------------------------
__global__ void k_conv(const float* __restrict__ wqkv, const float* __restrict__ wout,
                       short* __restrict__ wb)
{
    int i = (blockIdx.x * 256 + threadIdx.x) * 4;
    const float* src = (i < ROWS_ * C_) ? (wqkv + i) : (wout + (i - ROWS_ * C_));
    float4 f = *reinterpret_cast<const float4*>(src);
    short4 s;
    s.x = f2bf(f.x); s.y = f2bf(f.y); s.z = f2bf(f.z); s.w = f2bf(f.w);
    *reinterpret_cast<short4*>(wb + i) = s;
}

// ------------------------------------------------------------------
// Kernel 1: round-6 structure with smQ DELETED: LDS = 32 KB exactly
// -> 5 blocks/CU. q~ stored direct from regs in [b][hid][n] layout
// (each store = 64 lanes x 2B consecutive n = 128B coalesced).
// 3 barriers total. No atomics (partials, as round 6).
// ------------------------------------------------------------------
__global__ __launch_bounds__(256, 4) void k_qkv(
    const float* __restrict__ x, const short* __restrict__ wbf,
    short* __restrict__ qtb, short* __restrict__ part16,
    float* __restrict__ partden)
{
    __shared__ __align__(16) char smA[32768];  // x tile [64 n][256 k] bf16 swz16B;
                                               // becomes ek/v tiles after MFMA

    const int blk = blockIdx.x;
    const int b   = blk >> 8;              // 256 col-blocks per batch
    const int n0  = (blk & 255) << 6;
    const int t   = threadIdx.x;
    const int l   = t & 63;
    const int wv  = t >> 6;
    const int c31 = l & 31;
    const int hf  = l >> 5;

    // ---- stage x tile [256 k][64 n] -> bf16 transposed swizzled [n][k] ----
    {
        const int kg = t >> 4;             // 0..15
        const int n4 = (t & 15) * 4;
        const float* xb = x + (size_t)b * C_ * N_ + n0 + n4;
#pragma unroll
        for (int it = 0; it < 4; it++) {
            const int k = it * 64 + kg * 4;
            const float* xp = xb + (size_t)k * N_;
            float4 r0 = *(const float4*)(xp);
            float4 r1 = *(const float4*)(xp + N_);
            float4 r2 = *(const float4*)(xp + 2 * (size_t)N_);
            float4 r3 = *(const float4*)(xp + 3 * (size_t)N_);
#define WRT(J, FLD) { short4 sv; sv.x = f2bf(r0.FLD); sv.y = f2bf(r1.FLD); \
    sv.z = f2bf(r2.FLD); sv.w = f2bf(r3.FLD); \
    int n_ = n4 + J; int ad_ = n_ * 512 + ((2 * k) ^ ((n_ & 31) << 4)); \
    *(short4*)(smA + ad_) = sv; }
            WRT(0, x) WRT(1, y) WRT(2, z) WRT(3, w)
#undef WRT
        }
    }
    __syncthreads();

    // ---- MFMA K-loop: 16 k-steps of 16 ----
    f32x16 acc[3][2];
#pragma unroll
    for (int ti = 0; ti < 3; ti++)
#pragma unroll
        for (int ct = 0; ct < 2; ct++)
#pragma unroll
            for (int r = 0; r < 16; r++) acc[ti][ct][r] = 0.f;

#pragma unroll
    for (int ks = 0; ks < 16; ks++) {
        const int k0   = ks * 16 + hf * 8;
        const int slot = 2 * ks + hf;
        bf16x8 bfr0 = *(const bf16x8*)(smA + (c31)      * 512 + 16 * (slot ^ c31));
        bf16x8 bfr1 = *(const bf16x8*)(smA + (c31 + 32) * 512 + 16 * (slot ^ c31));
#pragma unroll
        for (int ti = 0; ti < 3; ti++) {
            const int row = (wv + ti * 4) * 32 + c31;
            bf16x8 af = *(const bf16x8*)(wbf + row * C_ + k0);
            acc[ti][0] = __builtin_amdgcn_mfma_f32_32x32x16_bf16(af, bfr0, acc[ti][0], 0, 0, 0);
            acc[ti][1] = __builtin_amdgcn_mfma_f32_32x32x16_bf16(af, bfr1, acc[ti][1], 0, 0, 0);
        }
    }

    // C layout: col = lane&31, row = (r&3)+8*(r>>2)+4*hf

    // ---- q softmax -> direct coalesced global store, [b][hid][n] layout ----
    // (pure regs + 128B-coalesced stores; overlaps other waves' MFMA tail)
#pragma unroll
    for (int ct = 0; ct < 2; ct++) {
        float mx = -1e30f;
#pragma unroll
        for (int r = 0; r < 16; r++) mx = fmaxf(mx, acc[0][ct][r]);
        mx = fmaxf(mx, __shfl_xor(mx, 32));
        float e[16]; float s = 0.f;
#pragma unroll
        for (int r = 0; r < 16; r++) { e[r] = __expf(acc[0][ct][r] - mx); s += e[r]; }
        s += __shfl_xor(s, 32);
        float inv = SCALE / s;
        short* qp = qtb + ((size_t)b * HID_ + wv * 32) * N_ + n0 + ct * 32 + c31;
#pragma unroll
        for (int r = 0; r < 16; r++) {
            int rm = (r & 3) + 8 * (r >> 2) + 4 * hf;
            qp[(size_t)rm * N_] = f2bf(e[r] * inv);
        }
    }
    __syncthreads();   // all MFMA reads of smA complete

    // ---- ek/v -> swizzled bf16 tiles (overwrite smA) ----
    char* ekb = smA + wv * 8192;
    char* vvb = ekb + 4096;
#pragma unroll
    for (int ct = 0; ct < 2; ct++)
#pragma unroll
        for (int r = 0; r < 16; r++) {
            int rm = (r & 3) + 8 * (r >> 2) + 4 * hf;
            int n  = ct * 32 + c31;
            int ad = rm * 128 + ((2 * n) ^ ((rm & 7) << 4));
            *(short*)(ekb + ad) = f2bf(__expf(acc[1][ct][r]));
            *(short*)(vvb + ad) = f2bf(acc[2][ct][r]);
        }
    __syncthreads();   // ek/v visible

    // ---- ctx MFMA: ctx[d][e] = sum_n ek[d,n] v[e,n] (this block's 64 n) ----
    f32x16 cD, dD;
#pragma unroll
    for (int r = 0; r < 16; r++) { cD[r] = 0.f; dD[r] = 0.f; }
    bf16x8 ones;
#pragma unroll
    for (int i = 0; i < 8; i++) ones[i] = (short)0x3F80;   // bf16 1.0
#pragma unroll
    for (int ks = 0; ks < 4; ks++) {
        int slot = 2 * ks + hf;
        bf16x8 ea = *(const bf16x8*)(ekb + c31 * 128 + 16 * (slot ^ (c31 & 7)));
        bf16x8 vb = *(const bf16x8*)(vvb + c31 * 128 + 16 * (slot ^ (c31 & 7)));
        cD = __builtin_amdgcn_mfma_f32_32x32x16_bf16(ea, vb,   cD, 0, 0, 0);
        dD = __builtin_amdgcn_mfma_f32_32x32x16_bf16(ea, ones, dD, 0, 0, 0);
    }

    // ---- store per-block ctx partials: bf16 ctx + f32 den (NO atomics) ----
    short* pb = part16 + ((size_t)blk * 4 + wv) * 1024;
#pragma unroll
    for (int r = 0; r < 16; r++) {
        int rm = (r & 3) + 8 * (r >> 2) + 4 * hf;
        pb[rm * 32 + c31] = f2bf(cD[r]);
    }
    if (c31 == 0) {
        float* pd = partden + ((size_t)blk * 4 + wv) * 32;
#pragma unroll
        for (int r = 0; r < 16; r++) {
            int rm = (r & 3) + 8 * (r >> 2) + 4 * hf;
            pd[rm] = dD[r];
        }
    }
}

// ------------------------------------------------------------------
// Kernel 1.5: reduce 256 partials per (b,h), divide by denom,
//             emit bf16 ctx^T [b][h][e][d]
// ------------------------------------------------------------------
__global__ __launch_bounds__(256) void k_red(
    const short* __restrict__ part16, const float* __restrict__ partden,
    short* __restrict__ ctxbf)
{
    __shared__ float den_s[32];
    const int bh = blockIdx.x;            // 32 = b*4 + h
    const int b  = bh >> 2, h = bh & 3;
    const int t  = threadIdx.x;
    const int d  = t >> 3;
    const int e4 = (t & 7) * 4;

    const short* p0 = part16 + ((size_t)(b * 256) * 4 + h) * 1024 + d * 32 + e4;
    float s0 = 0.f, s1 = 0.f, s2 = 0.f, s3 = 0.f;
    for (int q = 0; q < 256; q++) {
        short4 v = *(const short4*)(p0 + (size_t)q * 4096);
        s0 += bf2f(v.x); s1 += bf2f(v.y); s2 += bf2f(v.z); s3 += bf2f(v.w);
    }
    if ((t & 7) == 0) {
        const float* pd = partden + ((size_t)(b * 256) * 4 + h) * 32 + d;
        float ds = 0.f;
        for (int q = 0; q < 256; q++) ds += pd[(size_t)q * 128];
        den_s[d] = ds;
    }
    __syncthreads();
    float inv = 1.0f / den_s[d];
    short* cb = ctxbf + (size_t)bh * 1024 + d;     // [e][d] layout
    cb[(e4 + 0) * 32] = f2bf(s0 * inv);
    cb[(e4 + 1) * 32] = f2bf(s1 * inv);
    cb[(e4 + 2) * 32] = f2bf(s2 * inv);
    cb[(e4 + 3) * 32] = f2bf(s3 * inv);
}

// ------------------------------------------------------------------
// Kernel 2: hidden = ctx^T @ q~ (MFMA, ctx from global bf16),
//           y = w_out @ hidden (MFMA) + bias, RMSNorm over c, store.
//           q~ is now [b][hid][n]: B-frags built from 8 strided loads.
// ------------------------------------------------------------------
__global__ __launch_bounds__(256, 3) void k_out(
    const short* __restrict__ qtb, const short* __restrict__ ctxbf,
    const short* __restrict__ woutb, const float* __restrict__ bout,
    const float* __restrict__ g, float* __restrict__ out)
{
    __shared__ __align__(16) char  hidS[16384];        // [n][128] bf16 swz16B
    __shared__ float gl[C_], bl[C_];
    __shared__ float red[4][64];
    __shared__ float nrm[64];

    const int blk = blockIdx.x;
    const int b   = blk >> 8;
    const int n0  = (blk & 255) << 6;
    const int t   = threadIdx.x;
    const int l   = t & 63;
    const int wv  = t >> 6;
    const int c31 = l & 31;
    const int hf  = l >> 5;

    gl[t] = g[t];
    bl[t] = bout[t];
    __syncthreads();

    // ---- hidden MFMA: wave wv -> head wv; hid[e][n] = sum_d ctxT[e][d] q~[d][n]
    f32x16 hD[2];
#pragma unroll
    for (int ct = 0; ct < 2; ct++)
#pragma unroll
        for (int r = 0; r < 16; r++) hD[ct][r] = 0.f;
    const short* qb = qtb + (size_t)b * HID_ * N_ + n0;
    const short* cb = ctxbf + ((size_t)(b * H_ + wv) * 32 + c31) * 32;
#pragma unroll
    for (int ks = 0; ks < 2; ks++) {
        int k0 = ks * 16 + hf * 8;
        bf16x8 af = *(const bf16x8*)(cb + k0);
#pragma unroll
        for (int ct = 0; ct < 2; ct++) {
            bf16x8 bq;
#pragma unroll
            for (int i = 0; i < 8; i++)
                bq[i] = qb[(size_t)(wv * 32 + k0 + i) * N_ + ct * 32 + c31];
            hD[ct] = __builtin_amdgcn_mfma_f32_32x32x16_bf16(af, bq, hD[ct], 0, 0, 0);
        }
    }
    // write hidden -> swizzled LDS [n][hfull]
#pragma unroll
    for (int ct = 0; ct < 2; ct++)
#pragma unroll
        for (int r = 0; r < 16; r++) {
            int rm = (r & 3) + 8 * (r >> 2) + 4 * hf;
            int hfull = wv * 32 + rm;
            int n = ct * 32 + c31;
            int ad = n * 256 + ((2 * hfull) ^ ((n & 15) << 4));
            *(short*)(hidS + ad) = f2bf(hD[ct][r]);
        }
    __syncthreads();

    // ---- w_out GEMM: wave wv -> c rows wv*64..+64 ----
    f32x16 yacc[2][2];
#pragma unroll
    for (int rt = 0; rt < 2; rt++)
#pragma unroll
        for (int ct = 0; ct < 2; ct++)
#pragma unroll
            for (int r = 0; r < 16; r++) yacc[rt][ct][r] = 0.f;

#pragma unroll
    for (int ks = 0; ks < 8; ks++) {
        int k0 = ks * 16 + hf * 8;
        int sx = 2 * ks + hf;
        bf16x8 bq0 = *(const bf16x8*)(hidS + (c31)      * 256 + 16 * (sx ^ (c31 & 15)));
        bf16x8 bq1 = *(const bf16x8*)(hidS + (c31 + 32) * 256 + 16 * (sx ^ (c31 & 15)));
#pragma unroll
        for (int rt = 0; rt < 2; rt++) {
            bf16x8 af = *(const bf16x8*)(woutb + (wv * 64 + rt * 32 + c31) * HID_ + k0);
            yacc[rt][0] = __builtin_amdgcn_mfma_f32_32x32x16_bf16(af, bq0, yacc[rt][0], 0, 0, 0);
            yacc[rt][1] = __builtin_amdgcn_mfma_f32_32x32x16_bf16(af, bq1, yacc[rt][1], 0, 0, 0);
        }
    }

    // ---- bias + RMS over c ----
#pragma unroll
    for (int rt = 0; rt < 2; rt++)
#pragma unroll
        for (int r = 0; r < 16; r++) {
            int rm = (r & 3) + 8 * (r >> 2) + 4 * hf;
            float bo = bl[wv * 64 + rt * 32 + rm];
            yacc[rt][0][r] += bo;
            yacc[rt][1][r] += bo;
        }
#pragma unroll
    for (int ct = 0; ct < 2; ct++) {
        float s = 0.f;
#pragma unroll
        for (int rt = 0; rt < 2; rt++)
#pragma unroll
            for (int r = 0; r < 16; r++) s = fmaf(yacc[rt][ct][r], yacc[rt][ct][r], s);
        s += __shfl_xor(s, 32);
        if (hf == 0) red[wv][ct * 32 + c31] = s;
    }
    __syncthreads();
    if (t < 64) {
        float S = red[0][t] + red[1][t] + red[2][t] + red[3][t];
        nrm[t] = 16.0f / fmaxf(sqrtf(S), 1e-12f);
    }
    __syncthreads();

    float* ob = out + (size_t)b * C_ * N_ + n0;
#pragma unroll
    for (int rt = 0; rt < 2; rt++)
#pragma unroll
        for (int r = 0; r < 16; r++) {
            int rm = (r & 3) + 8 * (r >> 2) + 4 * hf;
            int c  = wv * 64 + rt * 32 + rm;
            float gc = gl[c];
#pragma unroll
            for (int ct = 0; ct < 2; ct++) {
                int n = ct * 32 + c31;
                ob[(size_t)c * N_ + n] = yacc[rt][ct][r] * gc * nrm[n];
            }
        }
}

// ------------------------------------------------------------------
extern "C" void kernel_launch(void* const* d_in, const int* in_sizes, int n_in,
                              void* d_out, int out_size, void* d_ws, size_t ws_size,
                              hipStream_t stream)
{
    const float* x    = (const float*)d_in[0];
    const float* wqkv = (const float*)d_in[1];
    const float* wout = (const float*)d_in[2];
    const float* bout = (const float*)d_in[3];
    const float* g    = (const float*)d_in[4];
    float* out = (float*)d_out;

    // ws: qtb bf16 [B][HID][N] (33.6 MB) | part16 bf16 [2048][4][1024] (16.8 MB)
    //   | partden f32 [2048][4][32] (1.05 MB) | ctxbf bf16 [B][H][32][32] (64 KB)
    //   | w bf16 (~0.26 MB)
    short* qtb     = (short*)d_ws;
    short* part16  = qtb + (size_t)B_ * N_ * HID_;
    float* partden = (float*)(part16 + (size_t)2048 * 4 * 1024);
    short* ctxbf   = (short*)(partden + (size_t)2048 * 4 * 32);
    short* wbf     = ctxbf + (size_t)B_ * H_ * 32 * 32;
    short* woutb   = wbf + ROWS_ * C_;

    k_conv<<<(ROWS_ * C_ + C_ * HID_) / 1024, 256, 0, stream>>>(wqkv, wout, wbf);
    k_qkv<<<B_ * (N_ / 64), 256, 0, stream>>>(x, wbf, qtb, part16, partden);
    k_red<<<B_ * H_, 256, 0, stream>>>(part16, partden, ctxbf);
    k_out<<<B_ * (N_ / 64), 256, 0, stream>>>(qtb, ctxbf, woutb, bout, g, out);
}

// Round 8
// 140.708 us; speedup vs baseline: 1.9245x; 1.0797x over previous
//
#include <hip/hip_runtime.h>
#include <hip/hip_bf16.h>
#include <math.h>

#define B_    8
#define C_    256
#define N_    16384
#define H_    4
#define D_    32
#define HID_  128
#define ROWS_ 384
#define SCALE 0.17677669529663687f   // 32^-0.5

typedef __attribute__((ext_vector_type(8))) short bf16x8;
typedef __attribute__((ext_vector_type(16))) float f32x16;

__device__ __forceinline__ short f2bf(float f) {
    union { __hip_bfloat16 h; short s; } u;
    u.h = __float2bfloat16(f);
    return u.s;
}
__device__ __forceinline__ float bf2f(short s) {
    union { unsigned u; float f; } x;
    x.u = ((unsigned)(unsigned short)s) << 16;
    return x.f;
}

// ------------------------------------------------------------------
// Kernel 0: build (a) fragment-major bf16 qkv weights:
//   wrearr[tile 0..11][ks 0..15][lane 0..63] = 16B fragment
//   lane l: row = tile*32 + (l&31), k = ks*16 + (l>>5)*8 .. +8
// so each wave A-frag load is 64 consecutive 16B chunks (coalesced).
// (b) woutb: plain bf16 row-major w_out (unchanged from round 7).
// ------------------------------------------------------------------
__global__ __launch_bounds__(256) void k_conv(
    const float* __restrict__ wqkv, const float* __restrict__ wout,
    short* __restrict__ wrearr, short* __restrict__ woutb)
{
    int i = blockIdx.x * 256 + threadIdx.x;
    if (i < 12288) {
        int tile = i >> 10;
        int ks   = (i >> 6) & 15;
        int l    = i & 63;
        int row  = tile * 32 + (l & 31);
        int k0   = ks * 16 + (l >> 5) * 8;
        const float* src = wqkv + row * 256 + k0;
        float4 f0 = *(const float4*)(src);
        float4 f1 = *(const float4*)(src + 4);
        short o[8] = {f2bf(f0.x), f2bf(f0.y), f2bf(f0.z), f2bf(f0.w),
                      f2bf(f1.x), f2bf(f1.y), f2bf(f1.z), f2bf(f1.w)};
        *(uint4*)(wrearr + (size_t)i * 8) = *(uint4*)o;
    } else {
        int j = (i - 12288) * 4;
        float4 f = *(const float4*)(wout + j);
        short4 s; s.x = f2bf(f.x); s.y = f2bf(f.y); s.z = f2bf(f.z); s.w = f2bf(f.w);
        *(short4*)(woutb + j) = s;
    }
}

// ------------------------------------------------------------------
// Kernel 1: identical to round 7 except A-fragments come from the
// fragment-major wrearr (coalesced 1KB loads) with a 1-deep prefetch.
// ------------------------------------------------------------------
__global__ __launch_bounds__(256, 4) void k_qkv(
    const float* __restrict__ x, const short* __restrict__ wrearr,
    short* __restrict__ qtb, short* __restrict__ part16,
    float* __restrict__ partden)
{
    __shared__ __align__(16) char smA[32768];  // x tile [64 n][256 k] bf16 swz16B;
                                               // becomes ek/v tiles after MFMA

    const int blk = blockIdx.x;
    const int b   = blk >> 8;              // 256 col-blocks per batch
    const int n0  = (blk & 255) << 6;
    const int t   = threadIdx.x;
    const int l   = t & 63;
    const int wv  = t >> 6;
    const int c31 = l & 31;
    const int hf  = l >> 5;

    // ---- stage x tile [256 k][64 n] -> bf16 transposed swizzled [n][k] ----
    {
        const int kg = t >> 4;             // 0..15
        const int n4 = (t & 15) * 4;
        const float* xb = x + (size_t)b * C_ * N_ + n0 + n4;
#pragma unroll
        for (int it = 0; it < 4; it++) {
            const int k = it * 64 + kg * 4;
            const float* xp = xb + (size_t)k * N_;
            float4 r0 = *(const float4*)(xp);
            float4 r1 = *(const float4*)(xp + N_);
            float4 r2 = *(const float4*)(xp + 2 * (size_t)N_);
            float4 r3 = *(const float4*)(xp + 3 * (size_t)N_);
#define WRT(J, FLD) { short4 sv; sv.x = f2bf(r0.FLD); sv.y = f2bf(r1.FLD); \
    sv.z = f2bf(r2.FLD); sv.w = f2bf(r3.FLD); \
    int n_ = n4 + J; int ad_ = n_ * 512 + ((2 * k) ^ ((n_ & 31) << 4)); \
    *(short4*)(smA + ad_) = sv; }
            WRT(0, x) WRT(1, y) WRT(2, z) WRT(3, w)
#undef WRT
        }
    }
    __syncthreads();

    // ---- MFMA K-loop: 16 k-steps of 16; A-frags coalesced + prefetched ----
    f32x16 acc[3][2];
#pragma unroll
    for (int ti = 0; ti < 3; ti++)
#pragma unroll
        for (int ct = 0; ct < 2; ct++)
#pragma unroll
            for (int r = 0; r < 16; r++) acc[ti][ct][r] = 0.f;

    // frag(ti, ks) = wp[ti*4096 + ks*64]   (tile = wv + ti*4, stride 1024 frags)
    const bf16x8* wp = (const bf16x8*)wrearr + (size_t)wv * 1024 + l;
    bf16x8 afN0 = wp[0], afN1 = wp[4096], afN2 = wp[8192];
#pragma unroll
    for (int ks = 0; ks < 16; ks++) {
        bf16x8 af0 = afN0, af1 = afN1, af2 = afN2;
        if (ks < 15) {
            afN0 = wp[(ks + 1) * 64];
            afN1 = wp[4096 + (ks + 1) * 64];
            afN2 = wp[8192 + (ks + 1) * 64];
        }
        const int slot = 2 * ks + hf;
        bf16x8 bfr0 = *(const bf16x8*)(smA + (c31)      * 512 + 16 * (slot ^ c31));
        bf16x8 bfr1 = *(const bf16x8*)(smA + (c31 + 32) * 512 + 16 * (slot ^ c31));
        acc[0][0] = __builtin_amdgcn_mfma_f32_32x32x16_bf16(af0, bfr0, acc[0][0], 0, 0, 0);
        acc[0][1] = __builtin_amdgcn_mfma_f32_32x32x16_bf16(af0, bfr1, acc[0][1], 0, 0, 0);
        acc[1][0] = __builtin_amdgcn_mfma_f32_32x32x16_bf16(af1, bfr0, acc[1][0], 0, 0, 0);
        acc[1][1] = __builtin_amdgcn_mfma_f32_32x32x16_bf16(af1, bfr1, acc[1][1], 0, 0, 0);
        acc[2][0] = __builtin_amdgcn_mfma_f32_32x32x16_bf16(af2, bfr0, acc[2][0], 0, 0, 0);
        acc[2][1] = __builtin_amdgcn_mfma_f32_32x32x16_bf16(af2, bfr1, acc[2][1], 0, 0, 0);
    }

    // C layout: col = lane&31, row = (r&3)+8*(r>>2)+4*hf

    // ---- q softmax -> direct coalesced global store, [b][hid][n] layout ----
#pragma unroll
    for (int ct = 0; ct < 2; ct++) {
        float mx = -1e30f;
#pragma unroll
        for (int r = 0; r < 16; r++) mx = fmaxf(mx, acc[0][ct][r]);
        mx = fmaxf(mx, __shfl_xor(mx, 32));
        float e[16]; float s = 0.f;
#pragma unroll
        for (int r = 0; r < 16; r++) { e[r] = __expf(acc[0][ct][r] - mx); s += e[r]; }
        s += __shfl_xor(s, 32);
        float inv = SCALE / s;
        short* qp = qtb + ((size_t)b * HID_ + wv * 32) * N_ + n0 + ct * 32 + c31;
#pragma unroll
        for (int r = 0; r < 16; r++) {
            int rm = (r & 3) + 8 * (r >> 2) + 4 * hf;
            qp[(size_t)rm * N_] = f2bf(e[r] * inv);
        }
    }
    __syncthreads();   // all MFMA reads of smA complete

    // ---- ek/v -> swizzled bf16 tiles (overwrite smA) ----
    char* ekb = smA + wv * 8192;
    char* vvb = ekb + 4096;
#pragma unroll
    for (int ct = 0; ct < 2; ct++)
#pragma unroll
        for (int r = 0; r < 16; r++) {
            int rm = (r & 3) + 8 * (r >> 2) + 4 * hf;
            int n  = ct * 32 + c31;
            int ad = rm * 128 + ((2 * n) ^ ((rm & 7) << 4));
            *(short*)(ekb + ad) = f2bf(__expf(acc[1][ct][r]));
            *(short*)(vvb + ad) = f2bf(acc[2][ct][r]);
        }
    __syncthreads();   // ek/v visible

    // ---- ctx MFMA: ctx[d][e] = sum_n ek[d,n] v[e,n] (this block's 64 n) ----
    f32x16 cD, dD;
#pragma unroll
    for (int r = 0; r < 16; r++) { cD[r] = 0.f; dD[r] = 0.f; }
    bf16x8 ones;
#pragma unroll
    for (int i = 0; i < 8; i++) ones[i] = (short)0x3F80;   // bf16 1.0
#pragma unroll
    for (int ks = 0; ks < 4; ks++) {
        int slot = 2 * ks + hf;
        bf16x8 ea = *(const bf16x8*)(ekb + c31 * 128 + 16 * (slot ^ (c31 & 7)));
        bf16x8 vb = *(const bf16x8*)(vvb + c31 * 128 + 16 * (slot ^ (c31 & 7)));
        cD = __builtin_amdgcn_mfma_f32_32x32x16_bf16(ea, vb,   cD, 0, 0, 0);
        dD = __builtin_amdgcn_mfma_f32_32x32x16_bf16(ea, ones, dD, 0, 0, 0);
    }

    // ---- store per-block ctx partials: bf16 ctx + f32 den (NO atomics) ----
    short* pb = part16 + ((size_t)blk * 4 + wv) * 1024;
#pragma unroll
    for (int r = 0; r < 16; r++) {
        int rm = (r & 3) + 8 * (r >> 2) + 4 * hf;
        pb[rm * 32 + c31] = f2bf(cD[r]);
    }
    if (c31 == 0) {
        float* pd = partden + ((size_t)blk * 4 + wv) * 32;
#pragma unroll
        for (int r = 0; r < 16; r++) {
            int rm = (r & 3) + 8 * (r >> 2) + 4 * hf;
            pd[rm] = dD[r];
        }
    }
}

// ------------------------------------------------------------------
// Kernel 1.5: reduce 256 partials per (b,h), divide by denom,
//             emit bf16 ctx^T [b][h][e][d]
// ------------------------------------------------------------------
__global__ __launch_bounds__(256) void k_red(
    const short* __restrict__ part16, const float* __restrict__ partden,
    short* __restrict__ ctxbf)
{
    __shared__ float den_s[32];
    const int bh = blockIdx.x;            // 32 = b*4 + h
    const int b  = bh >> 2, h = bh & 3;
    const int t  = threadIdx.x;
    const int d  = t >> 3;
    const int e4 = (t & 7) * 4;

    const short* p0 = part16 + ((size_t)(b * 256) * 4 + h) * 1024 + d * 32 + e4;
    float s0 = 0.f, s1 = 0.f, s2 = 0.f, s3 = 0.f;
    for (int q = 0; q < 256; q++) {
        short4 v = *(const short4*)(p0 + (size_t)q * 4096);
        s0 += bf2f(v.x); s1 += bf2f(v.y); s2 += bf2f(v.z); s3 += bf2f(v.w);
    }
    if ((t & 7) == 0) {
        const float* pd = partden + ((size_t)(b * 256) * 4 + h) * 32 + d;
        float ds = 0.f;
        for (int q = 0; q < 256; q++) ds += pd[(size_t)q * 128];
        den_s[d] = ds;
    }
    __syncthreads();
    float inv = 1.0f / den_s[d];
    short* cb = ctxbf + (size_t)bh * 1024 + d;     // [e][d] layout
    cb[(e4 + 0) * 32] = f2bf(s0 * inv);
    cb[(e4 + 1) * 32] = f2bf(s1 * inv);
    cb[(e4 + 2) * 32] = f2bf(s2 * inv);
    cb[(e4 + 3) * 32] = f2bf(s3 * inv);
}

// ------------------------------------------------------------------
// Kernel 2: hidden = ctx^T @ q~ (MFMA, ctx from global bf16),
//           y = w_out @ hidden (MFMA) + bias, RMSNorm over c, store.
//           q~ is [b][hid][n]: B-frags built from 8 strided loads.
// ------------------------------------------------------------------
__global__ __launch_bounds__(256, 3) void k_out(
    const short* __restrict__ qtb, const short* __restrict__ ctxbf,
    const short* __restrict__ woutb, const float* __restrict__ bout,
    const float* __restrict__ g, float* __restrict__ out)
{
    __shared__ __align__(16) char  hidS[16384];        // [n][128] bf16 swz16B
    __shared__ float gl[C_], bl[C_];
    __shared__ float red[4][64];
    __shared__ float nrm[64];

    const int blk = blockIdx.x;
    const int b   = blk >> 8;
    const int n0  = (blk & 255) << 6;
    const int t   = threadIdx.x;
    const int l   = t & 63;
    const int wv  = t >> 6;
    const int c31 = l & 31;
    const int hf  = l >> 5;

    gl[t] = g[t];
    bl[t] = bout[t];
    __syncthreads();

    // ---- hidden MFMA: wave wv -> head wv; hid[e][n] = sum_d ctxT[e][d] q~[d][n]
    f32x16 hD[2];
#pragma unroll
    for (int ct = 0; ct < 2; ct++)
#pragma unroll
        for (int r = 0; r < 16; r++) hD[ct][r] = 0.f;
    const short* qb = qtb + (size_t)b * HID_ * N_ + n0;
    const short* cb = ctxbf + ((size_t)(b * H_ + wv) * 32 + c31) * 32;
#pragma unroll
    for (int ks = 0; ks < 2; ks++) {
        int k0 = ks * 16 + hf * 8;
        bf16x8 af = *(const bf16x8*)(cb + k0);
#pragma unroll
        for (int ct = 0; ct < 2; ct++) {
            bf16x8 bq;
#pragma unroll
            for (int i = 0; i < 8; i++)
                bq[i] = qb[(size_t)(wv * 32 + k0 + i) * N_ + ct * 32 + c31];
            hD[ct] = __builtin_amdgcn_mfma_f32_32x32x16_bf16(af, bq, hD[ct], 0, 0, 0);
        }
    }
    // write hidden -> swizzled LDS [n][hfull]
#pragma unroll
    for (int ct = 0; ct < 2; ct++)
#pragma unroll
        for (int r = 0; r < 16; r++) {
            int rm = (r & 3) + 8 * (r >> 2) + 4 * hf;
            int hfull = wv * 32 + rm;
            int n = ct * 32 + c31;
            int ad = n * 256 + ((2 * hfull) ^ ((n & 15) << 4));
            *(short*)(hidS + ad) = f2bf(hD[ct][r]);
        }
    __syncthreads();

    // ---- w_out GEMM: wave wv -> c rows wv*64..+64 ----
    f32x16 yacc[2][2];
#pragma unroll
    for (int rt = 0; rt < 2; rt++)
#pragma unroll
        for (int ct = 0; ct < 2; ct++)
#pragma unroll
            for (int r = 0; r < 16; r++) yacc[rt][ct][r] = 0.f;

#pragma unroll
    for (int ks = 0; ks < 8; ks++) {
        int k0 = ks * 16 + hf * 8;
        int sx = 2 * ks + hf;
        bf16x8 bq0 = *(const bf16x8*)(hidS + (c31)      * 256 + 16 * (sx ^ (c31 & 15)));
        bf16x8 bq1 = *(const bf16x8*)(hidS + (c31 + 32) * 256 + 16 * (sx ^ (c31 & 15)));
#pragma unroll
        for (int rt = 0; rt < 2; rt++) {
            bf16x8 af = *(const bf16x8*)(woutb + (wv * 64 + rt * 32 + c31) * HID_ + k0);
            yacc[rt][0] = __builtin_amdgcn_mfma_f32_32x32x16_bf16(af, bq0, yacc[rt][0], 0, 0, 0);
            yacc[rt][1] = __builtin_amdgcn_mfma_f32_32x32x16_bf16(af, bq1, yacc[rt][1], 0, 0, 0);
        }
    }

    // ---- bias + RMS over c ----
#pragma unroll
    for (int rt = 0; rt < 2; rt++)
#pragma unroll
        for (int r = 0; r < 16; r++) {
            int rm = (r & 3) + 8 * (r >> 2) + 4 * hf;
            float bo = bl[wv * 64 + rt * 32 + rm];
            yacc[rt][0][r] += bo;
            yacc[rt][1][r] += bo;
        }
#pragma unroll
    for (int ct = 0; ct < 2; ct++) {
        float s = 0.f;
#pragma unroll
        for (int rt = 0; rt < 2; rt++)
#pragma unroll
            for (int r = 0; r < 16; r++) s = fmaf(yacc[rt][ct][r], yacc[rt][ct][r], s);
        s += __shfl_xor(s, 32);
        if (hf == 0) red[wv][ct * 32 + c31] = s;
    }
    __syncthreads();
    if (t < 64) {
        float S = red[0][t] + red[1][t] + red[2][t] + red[3][t];
        nrm[t] = 16.0f / fmaxf(sqrtf(S), 1e-12f);
    }
    __syncthreads();

    float* ob = out + (size_t)b * C_ * N_ + n0;
#pragma unroll
    for (int rt = 0; rt < 2; rt++)
#pragma unroll
        for (int r = 0; r < 16; r++) {
            int rm = (r & 3) + 8 * (r >> 2) + 4 * hf;
            int c  = wv * 64 + rt * 32 + rm;
            float gc = gl[c];
#pragma unroll
            for (int ct = 0; ct < 2; ct++) {
                int n = ct * 32 + c31;
                ob[(size_t)c * N_ + n] = yacc[rt][ct][r] * gc * nrm[n];
            }
        }
}

// ------------------------------------------------------------------
extern "C" void kernel_launch(void* const* d_in, const int* in_sizes, int n_in,
                              void* d_out, int out_size, void* d_ws, size_t ws_size,
                              hipStream_t stream)
{
    const float* x    = (const float*)d_in[0];
    const float* wqkv = (const float*)d_in[1];
    const float* wout = (const float*)d_in[2];
    const float* bout = (const float*)d_in[3];
    const float* g    = (const float*)d_in[4];
    float* out = (float*)d_out;

    // ws: qtb bf16 [B][HID][N] (33.6 MB) | part16 bf16 [2048][4][1024] (16.8 MB)
    //   | partden f32 [2048][4][32] (1.05 MB) | ctxbf bf16 [B][H][32][32] (64 KB)
    //   | wrearr bf16 12288x8 (196 KB) | woutb bf16 32768 (64 KB)
    short* qtb     = (short*)d_ws;
    short* part16  = qtb + (size_t)B_ * N_ * HID_;
    float* partden = (float*)(part16 + (size_t)2048 * 4 * 1024);
    short* ctxbf   = (short*)(partden + (size_t)2048 * 4 * 32);
    short* wrearr  = ctxbf + (size_t)B_ * H_ * 32 * 32;
    short* woutb   = wrearr + (size_t)12288 * 8;

    k_conv<<<80, 256, 0, stream>>>(wqkv, wout, wrearr, woutb);
    k_qkv<<<B_ * (N_ / 64), 256, 0, stream>>>(x, wrearr, qtb, part16, partden);
    k_red<<<B_ * H_, 256, 0, stream>>>(part16, partden, ctxbf);
    k_out<<<B_ * (N_ / 64), 256, 0, stream>>>(qtb, ctxbf, woutb, bout, g, out);
}

// Round 9
// 137.403 us; speedup vs baseline: 1.9708x; 1.0240x over previous
//
#include <hip/hip_runtime.h>
#include <hip/hip_bf16.h>
#include <math.h>

#define B_    8
#define C_    256
#define N_    16384
#define H_    4
#define D_    32
#define HID_  128
#define ROWS_ 384
#define SCALE 0.17677669529663687f   // 32^-0.5

typedef __attribute__((ext_vector_type(8))) short bf16x8;
typedef __attribute__((ext_vector_type(16))) float f32x16;

__device__ __forceinline__ short f2bf(float f) {
    union { __hip_bfloat16 h; short s; } u;
    u.h = __float2bfloat16(f);
    return u.s;
}
__device__ __forceinline__ float bf2f(short s) {
    union { unsigned u; float f; } x;
    x.u = ((unsigned)(unsigned short)s) << 16;
    return x.f;
}

// ------------------------------------------------------------------
// Kernel 0: build fragment-major bf16 qkv weights + bf16 w_out
// ------------------------------------------------------------------
__global__ __launch_bounds__(256) void k_conv(
    const float* __restrict__ wqkv, const float* __restrict__ wout,
    short* __restrict__ wrearr, short* __restrict__ woutb)
{
    int i = blockIdx.x * 256 + threadIdx.x;
    if (i < 12288) {
        int tile = i >> 10;
        int ks   = (i >> 6) & 15;
        int l    = i & 63;
        int row  = tile * 32 + (l & 31);
        int k0   = ks * 16 + (l >> 5) * 8;
        const float* src = wqkv + row * 256 + k0;
        float4 f0 = *(const float4*)(src);
        float4 f1 = *(const float4*)(src + 4);
        short o[8] = {f2bf(f0.x), f2bf(f0.y), f2bf(f0.z), f2bf(f0.w),
                      f2bf(f1.x), f2bf(f1.y), f2bf(f1.z), f2bf(f1.w)};
        *(uint4*)(wrearr + (size_t)i * 8) = *(uint4*)o;
    } else {
        int j = (i - 12288) * 4;
        float4 f = *(const float4*)(wout + j);
        short4 s; s.x = f2bf(f.x); s.y = f2bf(f.y); s.z = f2bf(f.z); s.w = f2bf(f.w);
        *(short4*)(woutb + j) = s;
    }
}

// ------------------------------------------------------------------
// Kernel 1: BN=128 (8 waves / 512 thr). Stage strips = 512B.
// LDS: x image [128n][256k] bf16 swz = 64KB, reused as 8x8KB ek/v.
// Wave w: head h=w&3, col-half ch=w>>2. 2 barriers/block.
// Partial layout matches round-8 k_red exactly (q = nwin*2+ch).
// XCD swizzle: each XCD streams one batch's contiguous x slab.
// ------------------------------------------------------------------
__global__ __launch_bounds__(512, 4) void k_qkv(
    const float* __restrict__ x, const short* __restrict__ wrearr,
    short* __restrict__ qtb, short* __restrict__ part16,
    float* __restrict__ partden)
{
    __shared__ __align__(16) char smA[65536];

    const int orig = blockIdx.x;
    const int swz  = (orig & 7) * 128 + (orig >> 3);   // bijective, 1024 = 8*128
    const int b    = swz >> 7;
    const int nwin = swz & 127;
    const int nb   = nwin << 7;          // 128-col window base
    const int t    = threadIdx.x;
    const int l    = t & 63;
    const int wv   = t >> 6;             // 0..7
    const int h    = wv & 3;
    const int ch   = wv >> 2;            // 0/1 column half
    const int c31  = l & 31;
    const int hf   = l >> 5;

    // ---- stage x tile [256 k][128 n] -> bf16 transposed swizzled [n][k] ----
    {
        const int kg = t >> 5;           // 0..15
        const int n4 = (t & 31) * 4;     // 0..124
        const float* xb = x + (size_t)b * C_ * N_ + nb + n4;
#pragma unroll
        for (int it = 0; it < 4; it++) {
            const int k = it * 64 + kg * 4;
            const float* xp = xb + (size_t)k * N_;
            float4 r0 = *(const float4*)(xp);
            float4 r1 = *(const float4*)(xp + N_);
            float4 r2 = *(const float4*)(xp + 2 * (size_t)N_);
            float4 r3 = *(const float4*)(xp + 3 * (size_t)N_);
#define WRT(J, FLD) { short4 sv; sv.x = f2bf(r0.FLD); sv.y = f2bf(r1.FLD); \
    sv.z = f2bf(r2.FLD); sv.w = f2bf(r3.FLD); \
    int n_ = n4 + J; int ad_ = n_ * 512 + ((2 * k) ^ ((n_ & 31) << 4)); \
    *(short4*)(smA + ad_) = sv; }
            WRT(0, x) WRT(1, y) WRT(2, z) WRT(3, w)
#undef WRT
        }
    }
    __syncthreads();

    // ---- MFMA K-loop: 16 k-steps of 16; A-frags coalesced + prefetched ----
    f32x16 acc[3][2];
#pragma unroll
    for (int ti = 0; ti < 3; ti++)
#pragma unroll
        for (int ct = 0; ct < 2; ct++)
#pragma unroll
            for (int r = 0; r < 16; r++) acc[ti][ct][r] = 0.f;

    const bf16x8* wp = (const bf16x8*)wrearr + (size_t)h * 1024 + l;
    bf16x8 afN0 = wp[0], afN1 = wp[4096], afN2 = wp[8192];
    const char* smB0 = smA + (ch * 64 + c31) * 512;
    const char* smB1 = smA + (ch * 64 + 32 + c31) * 512;
#pragma unroll
    for (int ks = 0; ks < 16; ks++) {
        bf16x8 af0 = afN0, af1 = afN1, af2 = afN2;
        if (ks < 15) {
            afN0 = wp[(ks + 1) * 64];
            afN1 = wp[4096 + (ks + 1) * 64];
            afN2 = wp[8192 + (ks + 1) * 64];
        }
        const int slot = 2 * ks + hf;
        bf16x8 bfr0 = *(const bf16x8*)(smB0 + 16 * (slot ^ c31));
        bf16x8 bfr1 = *(const bf16x8*)(smB1 + 16 * (slot ^ c31));
        acc[0][0] = __builtin_amdgcn_mfma_f32_32x32x16_bf16(af0, bfr0, acc[0][0], 0, 0, 0);
        acc[0][1] = __builtin_amdgcn_mfma_f32_32x32x16_bf16(af0, bfr1, acc[0][1], 0, 0, 0);
        acc[1][0] = __builtin_amdgcn_mfma_f32_32x32x16_bf16(af1, bfr0, acc[1][0], 0, 0, 0);
        acc[1][1] = __builtin_amdgcn_mfma_f32_32x32x16_bf16(af1, bfr1, acc[1][1], 0, 0, 0);
        acc[2][0] = __builtin_amdgcn_mfma_f32_32x32x16_bf16(af2, bfr0, acc[2][0], 0, 0, 0);
        acc[2][1] = __builtin_amdgcn_mfma_f32_32x32x16_bf16(af2, bfr1, acc[2][1], 0, 0, 0);
    }

    // C layout: col = lane&31, row = (r&3)+8*(r>>2)+4*hf

    // ---- q softmax -> direct coalesced global store, [b][hid][n] layout ----
#pragma unroll
    for (int ct = 0; ct < 2; ct++) {
        float mx = -1e30f;
#pragma unroll
        for (int r = 0; r < 16; r++) mx = fmaxf(mx, acc[0][ct][r]);
        mx = fmaxf(mx, __shfl_xor(mx, 32));
        float e[16]; float s = 0.f;
#pragma unroll
        for (int r = 0; r < 16; r++) { e[r] = __expf(acc[0][ct][r] - mx); s += e[r]; }
        s += __shfl_xor(s, 32);
        float inv = SCALE / s;
        short* qp = qtb + ((size_t)b * HID_ + h * 32) * N_ + nb + ch * 64 + ct * 32 + c31;
#pragma unroll
        for (int r = 0; r < 16; r++) {
            int rm = (r & 3) + 8 * (r >> 2) + 4 * hf;
            qp[(size_t)rm * N_] = f2bf(e[r] * inv);
        }
    }
    __syncthreads();   // all MFMA reads of smA complete across all 8 waves

    // ---- ek/v -> per-wave swizzled bf16 tiles (overwrite smA; own region) ----
    char* ekb = smA + wv * 8192;
    char* vvb = ekb + 4096;
#pragma unroll
    for (int ct = 0; ct < 2; ct++)
#pragma unroll
        for (int r = 0; r < 16; r++) {
            int rm = (r & 3) + 8 * (r >> 2) + 4 * hf;
            int n  = ct * 32 + c31;
            int ad = rm * 128 + ((2 * n) ^ ((rm & 7) << 4));
            *(short*)(ekb + ad) = f2bf(__expf(acc[1][ct][r]));
            *(short*)(vvb + ad) = f2bf(acc[2][ct][r]);
        }
    // no barrier: each wave reads only its own ekb/vvb (lgkmcnt suffices)

    // ---- ctx MFMA: ctx[d][e] = sum_n ek[d,n] v[e,n] (this wave's 64 n) ----
    f32x16 cD, dD;
#pragma unroll
    for (int r = 0; r < 16; r++) { cD[r] = 0.f; dD[r] = 0.f; }
    bf16x8 ones;
#pragma unroll
    for (int i = 0; i < 8; i++) ones[i] = (short)0x3F80;   // bf16 1.0
#pragma unroll
    for (int ks = 0; ks < 4; ks++) {
        int slot = 2 * ks + hf;
        bf16x8 ea = *(const bf16x8*)(ekb + c31 * 128 + 16 * (slot ^ (c31 & 7)));
        bf16x8 vb = *(const bf16x8*)(vvb + c31 * 128 + 16 * (slot ^ (c31 & 7)));
        cD = __builtin_amdgcn_mfma_f32_32x32x16_bf16(ea, vb,   cD, 0, 0, 0);
        dD = __builtin_amdgcn_mfma_f32_32x32x16_bf16(ea, ones, dD, 0, 0, 0);
    }

    // ---- store per-block ctx partials (layout identical to round 8) ----
    const int q64 = nwin * 2 + ch;       // 64-col tile index within batch, 0..255
    short* pb = part16 + ((size_t)(b * 256 + q64) * 4 + h) * 1024;
#pragma unroll
    for (int r = 0; r < 16; r++) {
        int rm = (r & 3) + 8 * (r >> 2) + 4 * hf;
        pb[rm * 32 + c31] = f2bf(cD[r]);
    }
    if (c31 == 0) {
        float* pd = partden + ((size_t)(b * 256 + q64) * 4 + h) * 32;
#pragma unroll
        for (int r = 0; r < 16; r++) {
            int rm = (r & 3) + 8 * (r >> 2) + 4 * hf;
            pd[rm] = dD[r];
        }
    }
}

// ------------------------------------------------------------------
// Kernel 1.5: reduce 256 partials per (b,h), divide by denom,
//             emit bf16 ctx^T [b][h][e][d]   (unchanged)
// ------------------------------------------------------------------
__global__ __launch_bounds__(256) void k_red(
    const short* __restrict__ part16, const float* __restrict__ partden,
    short* __restrict__ ctxbf)
{
    __shared__ float den_s[32];
    const int bh = blockIdx.x;            // 32 = b*4 + h
    const int b  = bh >> 2, h = bh & 3;
    const int t  = threadIdx.x;
    const int d  = t >> 3;
    const int e4 = (t & 7) * 4;

    const short* p0 = part16 + ((size_t)(b * 256) * 4 + h) * 1024 + d * 32 + e4;
    float s0 = 0.f, s1 = 0.f, s2 = 0.f, s3 = 0.f;
    for (int q = 0; q < 256; q++) {
        short4 v = *(const short4*)(p0 + (size_t)q * 4096);
        s0 += bf2f(v.x); s1 += bf2f(v.y); s2 += bf2f(v.z); s3 += bf2f(v.w);
    }
    if ((t & 7) == 0) {
        const float* pd = partden + ((size_t)(b * 256) * 4 + h) * 32 + d;
        float ds = 0.f;
        for (int q = 0; q < 256; q++) ds += pd[(size_t)q * 128];
        den_s[d] = ds;
    }
    __syncthreads();
    float inv = 1.0f / den_s[d];
    short* cb = ctxbf + (size_t)bh * 1024 + d;     // [e][d] layout
    cb[(e4 + 0) * 32] = f2bf(s0 * inv);
    cb[(e4 + 1) * 32] = f2bf(s1 * inv);
    cb[(e4 + 2) * 32] = f2bf(s2 * inv);
    cb[(e4 + 3) * 32] = f2bf(s3 * inv);
}

// ------------------------------------------------------------------
// Kernel 2: hidden = ctx^T @ q~ (MFMA), y = w_out @ hidden (MFMA)
//           + bias, RMSNorm over c, store.   (unchanged)
// ------------------------------------------------------------------
__global__ __launch_bounds__(256, 3) void k_out(
    const short* __restrict__ qtb, const short* __restrict__ ctxbf,
    const short* __restrict__ woutb, const float* __restrict__ bout,
    const float* __restrict__ g, float* __restrict__ out)
{
    __shared__ __align__(16) char  hidS[16384];        // [n][128] bf16 swz16B
    __shared__ float gl[C_], bl[C_];
    __shared__ float red[4][64];
    __shared__ float nrm[64];

    const int blk = blockIdx.x;
    const int b   = blk >> 8;
    const int n0  = (blk & 255) << 6;
    const int t   = threadIdx.x;
    const int l   = t & 63;
    const int wv  = t >> 6;
    const int c31 = l & 31;
    const int hf  = l >> 5;

    gl[t] = g[t];
    bl[t] = bout[t];
    __syncthreads();

    // ---- hidden MFMA: wave wv -> head wv; hid[e][n] = sum_d ctxT[e][d] q~[d][n]
    f32x16 hD[2];
#pragma unroll
    for (int ct = 0; ct < 2; ct++)
#pragma unroll
        for (int r = 0; r < 16; r++) hD[ct][r] = 0.f;
    const short* qb = qtb + (size_t)b * HID_ * N_ + n0;
    const short* cb = ctxbf + ((size_t)(b * H_ + wv) * 32 + c31) * 32;
#pragma unroll
    for (int ks = 0; ks < 2; ks++) {
        int k0 = ks * 16 + hf * 8;
        bf16x8 af = *(const bf16x8*)(cb + k0);
#pragma unroll
        for (int ct = 0; ct < 2; ct++) {
            bf16x8 bq;
#pragma unroll
            for (int i = 0; i < 8; i++)
                bq[i] = qb[(size_t)(wv * 32 + k0 + i) * N_ + ct * 32 + c31];
            hD[ct] = __builtin_amdgcn_mfma_f32_32x32x16_bf16(af, bq, hD[ct], 0, 0, 0);
        }
    }
    // write hidden -> swizzled LDS [n][hfull]
#pragma unroll
    for (int ct = 0; ct < 2; ct++)
#pragma unroll
        for (int r = 0; r < 16; r++) {
            int rm = (r & 3) + 8 * (r >> 2) + 4 * hf;
            int hfull = wv * 32 + rm;
            int n = ct * 32 + c31;
            int ad = n * 256 + ((2 * hfull) ^ ((n & 15) << 4));
            *(short*)(hidS + ad) = f2bf(hD[ct][r]);
        }
    __syncthreads();

    // ---- w_out GEMM: wave wv -> c rows wv*64..+64 ----
    f32x16 yacc[2][2];
#pragma unroll
    for (int rt = 0; rt < 2; rt++)
#pragma unroll
        for (int ct = 0; ct < 2; ct++)
#pragma unroll
            for (int r = 0; r < 16; r++) yacc[rt][ct][r] = 0.f;

#pragma unroll
    for (int ks = 0; ks < 8; ks++) {
        int k0 = ks * 16 + hf * 8;
        int sx = 2 * ks + hf;
        bf16x8 bq0 = *(const bf16x8*)(hidS + (c31)      * 256 + 16 * (sx ^ (c31 & 15)));
        bf16x8 bq1 = *(const bf16x8*)(hidS + (c31 + 32) * 256 + 16 * (sx ^ (c31 & 15)));
#pragma unroll
        for (int rt = 0; rt < 2; rt++) {
            bf16x8 af = *(const bf16x8*)(woutb + (wv * 64 + rt * 32 + c31) * HID_ + k0);
            yacc[rt][0] = __builtin_amdgcn_mfma_f32_32x32x16_bf16(af, bq0, yacc[rt][0], 0, 0, 0);
            yacc[rt][1] = __builtin_amdgcn_mfma_f32_32x32x16_bf16(af, bq1, yacc[rt][1], 0, 0, 0);
        }
    }

    // ---- bias + RMS over c ----
#pragma unroll
    for (int rt = 0; rt < 2; rt++)
#pragma unroll
        for (int r = 0; r < 16; r++) {
            int rm = (r & 3) + 8 * (r >> 2) + 4 * hf;
            float bo = bl[wv * 64 + rt * 32 + rm];
            yacc[rt][0][r] += bo;
            yacc[rt][1][r] += bo;
        }
#pragma unroll
    for (int ct = 0; ct < 2; ct++) {
        float s = 0.f;
#pragma unroll
        for (int rt = 0; rt < 2; rt++)
#pragma unroll
            for (int r = 0; r < 16; r++) s = fmaf(yacc[rt][ct][r], yacc[rt][ct][r], s);
        s += __shfl_xor(s, 32);
        if (hf == 0) red[wv][ct * 32 + c31] = s;
    }
    __syncthreads();
    if (t < 64) {
        float S = red[0][t] + red[1][t] + red[2][t] + red[3][t];
        nrm[t] = 16.0f / fmaxf(sqrtf(S), 1e-12f);
    }
    __syncthreads();

    float* ob = out + (size_t)b * C_ * N_ + n0;
#pragma unroll
    for (int rt = 0; rt < 2; rt++)
#pragma unroll
        for (int r = 0; r < 16; r++) {
            int rm = (r & 3) + 8 * (r >> 2) + 4 * hf;
            int c  = wv * 64 + rt * 32 + rm;
            float gc = gl[c];
#pragma unroll
            for (int ct = 0; ct < 2; ct++) {
                int n = ct * 32 + c31;
                ob[(size_t)c * N_ + n] = yacc[rt][ct][r] * gc * nrm[n];
            }
        }
}

// ------------------------------------------------------------------
extern "C" void kernel_launch(void* const* d_in, const int* in_sizes, int n_in,
                              void* d_out, int out_size, void* d_ws, size_t ws_size,
                              hipStream_t stream)
{
    const float* x    = (const float*)d_in[0];
    const float* wqkv = (const float*)d_in[1];
    const float* wout = (const float*)d_in[2];
    const float* bout = (const float*)d_in[3];
    const float* g    = (const float*)d_in[4];
    float* out = (float*)d_out;

    short* qtb     = (short*)d_ws;
    short* part16  = qtb + (size_t)B_ * N_ * HID_;
    float* partden = (float*)(part16 + (size_t)2048 * 4 * 1024);
    short* ctxbf   = (short*)(partden + (size_t)2048 * 4 * 32);
    short* wrearr  = ctxbf + (size_t)B_ * H_ * 32 * 32;
    short* woutb   = wrearr + (size_t)12288 * 8;

    k_conv<<<80, 256, 0, stream>>>(wqkv, wout, wrearr, woutb);
    k_qkv<<<1024, 512, 0, stream>>>(x, wrearr, qtb, part16, partden);
    k_red<<<B_ * H_, 256, 0, stream>>>(part16, partden, ctxbf);
    k_out<<<B_ * (N_ / 64), 256, 0, stream>>>(qtb, ctxbf, woutb, bout, g, out);
}